// Round 11
// baseline (1476.065 us; speedup 1.0000x reference)
//
#include <hip/hip_runtime.h>
#include <hip/hip_bf16.h>
#include <float.h>

// LiDAR BEV pipeline (fp32 I/O):
//   voxelize -> conv3d(1->32)+BN+ReLU -> conv3d(32->64)+BN+ReLU -> conv3d(64->64)+BN+ReLU -> max over D
// R10: 1.37ms. conv2mfma was store-amplification bound (WRITE 508MB for a 134MB tensor:
// 8B scattered stores -> partial-sector write-allocate; MfmaUtil 8.6%, VALUBusy 4.4%).
// R11: (1) conv2 epilogue transposes acc through the spent A-tile LDS -> 16B/lane fully
// coalesced stores (full 64B lines); halo re-zeroed per pair (transpose clobbers it).
// (2) DCHUNK 16->8 on both MFMA convs -> 1024 blocks (4/CU, was 2/CU).

#define VOXEL 0.0625f
#define D_ 128
#define H_ 128
#define W_ 32
#define HW_ (H_*W_)      // 4096
#define DHW_ (D_*H_*W_)  // 524288
#define B_ 2
#define EPSV 1e-5f
#define OUTN_ (B_*64*HW_) // 524288
#define NBUCK 128         // stats buckets

typedef __hip_bfloat16 bf16;
typedef __attribute__((ext_vector_type(8))) short short8;   // 8 bf16
typedef __attribute__((ext_vector_type(4))) short short4v;  // 4 bf16
typedef __attribute__((ext_vector_type(4))) float f32x4;

__device__ inline void gl_lds16(const void* g, void* l){
  // async global->LDS, 16B per lane; LDS dest = base + lane*16 (wave-uniform base)
  __builtin_amdgcn_global_load_lds(
      (const __attribute__((address_space(1))) unsigned int*)g,
      (__attribute__((address_space(3))) unsigned int*)l, 16, 0, 0);
}

// ---------------- init ----------------

__global__ void zero_kernel(float* __restrict__ p, int n){
  int i = blockIdx.x*blockDim.x + threadIdx.x;
  if (i < n) p[i] = 0.f;
}

// ---------------- voxelize ----------------

__global__ void min_kernel(const float* __restrict__ pc, float* __restrict__ mins, int N){
  const float* base = pc + (size_t)blockIdx.x * N;
  float m = FLT_MAX;
  for (int j = threadIdx.x; j < N; j += blockDim.x){
    float v = base[j];
    if (v != v) v = 0.f;          // NaN -> 0, matching reference
    m = fminf(m, v);
  }
  for (int off = 32; off > 0; off >>= 1)
    m = fminf(m, __shfl_xor(m, off, 64));
  __shared__ float red[4];
  int wave = threadIdx.x >> 6;
  if ((threadIdx.x & 63) == 0) red[wave] = m;
  __syncthreads();
  if (threadIdx.x == 0){
    float r = red[0];
    for (int k = 1; k < (int)(blockDim.x >> 6); ++k) r = fminf(r, red[k]);
    mins[blockIdx.x] = r;
  }
}

__global__ void scatter_kernel(const float* __restrict__ pc, const float* __restrict__ mins,
                               float* __restrict__ grid, int N){
  int idx = blockIdx.x*blockDim.x + threadIdx.x;
  if (idx >= B_*N) return;
  int b = idx / N, n = idx - b*N;
  float x = pc[((size_t)b*3 + 0)*N + n];
  float y = pc[((size_t)b*3 + 1)*N + n];
  float z = pc[((size_t)b*3 + 2)*N + n];
  if (x != x) x = 0.f;
  if (y != y) y = 0.f;
  if (z != z) z = 0.f;
  int ix = (int)floorf((x - mins[b*3+0]) / VOXEL);
  int iy = (int)floorf((y - mins[b*3+1]) / VOXEL);
  int iz = (int)floorf((z - mins[b*3+2]) / VOXEL);
  ix = min(max(ix, 0), D_-1);
  iy = min(max(iy, 0), H_-1);
  iz = min(max(iz, 0), W_-1);
  grid[(size_t)b*DHW_ + (size_t)ix*HW_ + iy*W_ + iz] = 1.0f;
}

// ---------------- weight reorders ----------------

__global__ void reorder_kernel(const float* __restrict__ w, float* __restrict__ wr, int CIN, int COUT){
  int idx = blockIdx.x*blockDim.x + threadIdx.x;
  int total = COUT*CIN*27;
  if (idx >= total) return;
  int o = idx / (CIN*27);
  int rem = idx - o*(CIN*27);
  int i = rem / 27;
  int k = rem - i*27;
  wr[(i*27 + k)*COUT + o] = w[idx];
}

// w3 (64,64,3,3,3) fp32 -> [tap][o][64 i] bf16
__global__ void reorder3b_kernel(const float* __restrict__ w, bf16* __restrict__ wb){
  int idx = blockIdx.x*blockDim.x + threadIdx.x;
  if (idx >= 64*64*27) return;
  int o = idx / (64*27);
  int rem = idx - o*(64*27);
  int i = rem / 27;
  int tap = rem - i*27;
  wb[((size_t)tap*64 + o)*64 + i] = __float2bfloat16(w[idx]);
}

// w2 (64,32,3,3,3) fp32 -> [tap][o][32 i] bf16
__global__ void reorder2b_kernel(const float* __restrict__ w, bf16* __restrict__ wb){
  int idx = blockIdx.x*blockDim.x + threadIdx.x;
  if (idx >= 64*32*27) return;
  int o = idx / (32*27);
  int rem = idx - o*(32*27);
  int i = rem / 27;
  int tap = rem - i*27;
  wb[((size_t)tap*64 + o)*32 + i] = __float2bfloat16(w[idx]);
}

// ---------------- fp32 conv inner (conv1-class kernels) ----------------

template<int HT, int OPT, int COUT>
__device__ inline void conv_inner(float (*xs)[HT+2][34], float (*wsm)[COUT],
                                  int w, int og, float (*acc)[OPT]){
  #pragma unroll
  for (int kd = 0; kd < 3; ++kd){
    float xr[HT+2][3];
    #pragma unroll
    for (int r = 0; r < HT+2; ++r)
      #pragma unroll
      for (int c = 0; c < 3; ++c)
        xr[r][c] = xs[kd][r][w + c];
    #pragma unroll
    for (int kh = 0; kh < 3; ++kh)
      #pragma unroll
      for (int kw = 0; kw < 3; ++kw){
        const float* wp = &wsm[kd*9 + kh*3 + kw][og*OPT];
        float wv[OPT];
        #pragma unroll
        for (int oo = 0; oo < OPT; ++oo) wv[oo] = wp[oo];
        #pragma unroll
        for (int h = 0; h < HT; ++h){
          float xv = xr[h + kh][kw];
          #pragma unroll
          for (int oo = 0; oo < OPT; ++oo)
            acc[h][oo] = fmaf(xv, wv[oo], acc[h][oo]);
        }
      }
  }
}

// ---------------- conv1 BN stats only (fallback path) ----------------

__global__ __launch_bounds__(256)
void convstats_kernel(const float* __restrict__ X, const float* __restrict__ WR,
                      const float* __restrict__ bias, float* __restrict__ stats){
  const int tid = threadIdx.x;
  const int w   = tid & 31;
  const int og  = tid >> 5;
  const int h0  = blockIdx.x * 8;
  const int d   = blockIdx.y;
  const int b   = blockIdx.z;
  const int bucket = d & (NBUCK - 1);

  __shared__ float xs[3][10][34];
  __shared__ float wsm[27][32];

  float acc[8][4];
  #pragma unroll
  for (int h = 0; h < 8; ++h)
    #pragma unroll
    for (int oo = 0; oo < 4; ++oo) acc[h][oo] = 0.f;

  for (int e = tid; e < 27*32; e += 256)
    ((float*)wsm)[e] = WR[e];
  for (int e = tid; e < 960; e += 256){
    int ds = e / 320; int rem = e - ds*320; int r = rem >> 5; int ww = rem & 31;
    int dd = d + ds - 1, hh = h0 + r - 1;
    float v = 0.f;
    if (dd >= 0 && dd < D_ && hh >= 0 && hh < H_)
      v = X[((size_t)b*D_ + dd)*HW_ + hh*W_ + ww];
    xs[ds][r][ww + 1] = v;
  }
  if (tid < 30){ int ds = tid/10, r = tid - ds*10; xs[ds][r][0] = 0.f; xs[ds][r][33] = 0.f; }
  __syncthreads();
  conv_inner<8, 4, 32>(xs, wsm, w, og, acc);

  #pragma unroll
  for (int oo = 0; oo < 4; ++oo){
    int o = og*4 + oo;
    float bo = bias[o];
    float s1 = 0.f, s2 = 0.f;
    #pragma unroll
    for (int h = 0; h < 8; ++h){
      float y = acc[h][oo] + bo;
      s1 += y;
      s2 = fmaf(y, y, s2);
    }
    for (int m = 16; m > 0; m >>= 1){
      s1 += __shfl_xor(s1, m, 32);
      s2 += __shfl_xor(s2, m, 32);
    }
    if (w == 0){
      atomicAdd(&stats[bucket*128 + o], s1);
      atomicAdd(&stats[bucket*128 + 32 + o], s2);
    }
  }
}

// ---------------- conv1 -> RAW x1 channel-last bf16 [b][d][h][w][32] + BN1 stats ----------------

__global__ __launch_bounds__(256)
void conv1act_kernel(const float* __restrict__ X, const float* __restrict__ WR,
                     const float* __restrict__ bias, bf16* __restrict__ X1,
                     float* __restrict__ stats){
  const int tid = threadIdx.x;
  const int w   = tid & 31;
  const int og  = tid >> 5;
  const int h0  = blockIdx.x * 8;
  const int d   = blockIdx.y;
  const int b   = blockIdx.z;
  const int bucket = d & (NBUCK - 1);

  __shared__ float xs[3][10][34];
  __shared__ float wsm[27][32];

  float acc[8][4];
  #pragma unroll
  for (int h = 0; h < 8; ++h)
    #pragma unroll
    for (int oo = 0; oo < 4; ++oo) acc[h][oo] = 0.f;

  for (int e = tid; e < 27*32; e += 256)
    ((float*)wsm)[e] = WR[e];
  for (int e = tid; e < 960; e += 256){
    int ds = e / 320; int rem = e - ds*320; int r = rem >> 5; int ww = rem & 31;
    int dd = d + ds - 1, hh = h0 + r - 1;
    float v = 0.f;
    if (dd >= 0 && dd < D_ && hh >= 0 && hh < H_)
      v = X[((size_t)b*D_ + dd)*HW_ + hh*W_ + ww];
    xs[ds][r][ww + 1] = v;
  }
  if (tid < 30){ int ds = tid/10, r = tid - ds*10; xs[ds][r][0] = 0.f; xs[ds][r][33] = 0.f; }
  __syncthreads();
  conv_inner<8, 4, 32>(xs, wsm, w, og, acc);

  float bo[4], psum[4], psq[4];
  #pragma unroll
  for (int oo = 0; oo < 4; ++oo){
    bo[oo] = bias[og*4 + oo]; psum[oo] = 0.f; psq[oo] = 0.f;
  }
  #pragma unroll
  for (int h = 0; h < 8; ++h){
    bf16 row[4];
    #pragma unroll
    for (int oo = 0; oo < 4; ++oo){
      float y = acc[h][oo] + bo[oo];
      row[oo] = __float2bfloat16(y);
      psum[oo] += y;
      psq[oo]  = fmaf(y, y, psq[oo]);
    }
    *(short4v*)&X1[((((size_t)b*D_ + d)*H_ + (h0 + h))*W_ + w)*32 + og*4] = *(short4v*)row;
  }
  #pragma unroll
  for (int oo = 0; oo < 4; ++oo){
    float s1 = psum[oo], s2 = psq[oo];
    for (int m = 16; m > 0; m >>= 1){
      s1 += __shfl_xor(s1, m, 32);
      s2 += __shfl_xor(s2, m, 32);
    }
    if (w == 0){
      int o = og*4 + oo;
      atomicAdd(&stats[bucket*128 + o], s1);
      atomicAdd(&stats[bucket*128 + 32 + o], s2);
    }
  }
}

// ---------------- fused12 (fp32 fallback path, writes raw x2 + BN2 stats) ----------------

__global__ __launch_bounds__(256)
void fused12_kernel(const float* __restrict__ G0, const float* __restrict__ WR1,
                    const float* __restrict__ B1, const float* __restrict__ SS1,
                    const float* __restrict__ WR2, const float* __restrict__ B2,
                    bf16* __restrict__ X2, float* __restrict__ stats){
  const int tid = threadIdx.x;
  const int w   = tid & 31;
  const int og  = tid >> 5;
  const int h0  = blockIdx.x * 8;
  const int d   = blockIdx.y;
  const int b   = blockIdx.z;
  const int bucket = d & (NBUCK - 1);

  __shared__ float gs[5][12][34];
  __shared__ float w1s[32][27];
  __shared__ float xs[3][10][34];
  __shared__ float wsm[27][64];

  for (int e = tid; e < 5*12*34; e += 256){
    int ds = e / 408; int rem = e - ds*408; int r = rem / 34; int c = rem - r*34;
    int dd = d - 2 + ds, hh = h0 - 2 + r, ww = c - 1;
    float v = 0.f;
    if (c >= 1 && c <= 32 && dd >= 0 && dd < D_ && hh >= 0 && hh < H_)
      v = G0[((size_t)b*D_ + dd)*HW_ + hh*W_ + ww];
    gs[ds][r][c] = v;
  }
  for (int e = tid; e < 864; e += 256){
    int i = e/27, k = e - 27*i;
    w1s[i][k] = WR1[k*32 + i];
  }

  float acc[8][8];
  #pragma unroll
  for (int h = 0; h < 8; ++h)
    #pragma unroll
    for (int oo = 0; oo < 8; ++oo) acc[h][oo] = 0.f;

  for (int i = 0; i < 32; ++i){
    __syncthreads();
    float a1 = SS1[i];
    float f1 = fmaf(a1, B1[i], SS1[32 + i]);
    for (int e = tid; e < 1020; e += 256){
      int ds = e / 340; int rem = e - ds*340; int r = rem / 34; int c = rem - r*34;
      float v = 0.f;
      int dd = d - 1 + ds, hh = h0 - 1 + r;
      if (c >= 1 && c <= 32 && dd >= 0 && dd < D_ && hh >= 0 && hh < H_){
        float s = 0.f;
        #pragma unroll
        for (int kd = 0; kd < 3; ++kd)
          #pragma unroll
          for (int kh = 0; kh < 3; ++kh)
            #pragma unroll
            for (int kw = 0; kw < 3; ++kw)
              s = fmaf(gs[ds+kd][r+kh][c-1+kw], w1s[i][kd*9+kh*3+kw], s);
        v = fmaxf(fmaf(a1, s, f1), 0.f);
      }
      xs[ds][r][c] = v;
    }
    for (int e = tid; e < 27*64; e += 256)
      ((float*)wsm)[e] = WR2[i*27*64 + e];
    __syncthreads();
    conv_inner<8, 8, 64>(xs, wsm, w, og, acc);
  }

  float bo[8], psum[8], psq[8];
  #pragma unroll
  for (int oo = 0; oo < 8; ++oo){ bo[oo] = B2[og*8 + oo]; psum[oo] = 0.f; psq[oo] = 0.f; }
  #pragma unroll
  for (int h = 0; h < 8; ++h){
    bf16 row[8];
    #pragma unroll
    for (int oo = 0; oo < 8; ++oo){
      float y = acc[h][oo] + bo[oo];
      row[oo] = __float2bfloat16(y);
      psum[oo] += y;
      psq[oo]  = fmaf(y, y, psq[oo]);
    }
    *(short8*)&X2[((((size_t)b*D_ + d)*H_ + (h0 + h))*W_ + w)*64 + og*8] = *(short8*)row;
  }
  #pragma unroll
  for (int oo = 0; oo < 8; ++oo){
    float s1 = psum[oo], s2 = psq[oo];
    for (int m = 16; m > 0; m >>= 1){
      s1 += __shfl_xor(s1, m, 32);
      s2 += __shfl_xor(s2, m, 32);
    }
    if (w == 0){
      atomicAdd(&stats[bucket*128 + og*8 + oo], s1);
      atomicAdd(&stats[bucket*128 + 64 + og*8 + oo], s2);
    }
  }
}

// ---------------- conv2 MFMA: weights=A (M=64 o), activations=B (N=32 w) ----------------
// Epilogue transposes acc through the spent A-tile LDS so every global store is a
// 16B/lane fully-coalesced line write (R10 showed 3.8x write amplification from 8B
// scattered stores). Halo zeroing runs per pair (transpose clobbers the tile).

template<int DCHUNK>
__global__ __launch_bounds__(256, 2)
void conv2mfma_kernel(const bf16* __restrict__ X1, const bf16* __restrict__ WB,
                      const float* __restrict__ B2, bf16* __restrict__ X2,
                      float* __restrict__ stats){
  const int tid  = threadIdx.x;
  const int lane = tid & 63;
  const int wv   = tid >> 6;        // wave id = h-row
  const int l15  = lane & 15;
  const int quad = lane >> 4;
  const int h0   = blockIdx.x * 4;
  const int d0   = blockIdx.y * DCHUNK;
  const int b    = blockIdx.z;
  const int bucket = ((int)blockIdx.x | ((int)blockIdx.y << 5)) & (NBUCK - 1);

  __shared__ __align__(16) bf16 at[4][6][34][32];   // 52,224 B; doubles as transpose buf

  f32x4 acc[2][4][2];               // [dp][mt][nt]
  float br[4][4], psum[4][4], psq[4][4];
  #pragma unroll
  for (int mt = 0; mt < 4; ++mt)
    #pragma unroll
    for (int rg = 0; rg < 4; ++rg){
      br[mt][rg] = B2[mt*16 + quad*4 + rg];
      psum[mt][rg] = 0.f; psq[mt][rg] = 0.f;
    }

  const int wlane = lane >> 2;
  const int cq    = lane & 3;
  // per-wave transpose region: [dp][w][72] bf16 (stride 72 keeps 16B alignment)
  bf16* tb = &at[0][0][0][0] + (size_t)wv * (2*32*72);

  for (int p = 0; p < DCHUNK/2; ++p){
    const int d = d0 + 2*p;
    #pragma unroll
    for (int dp = 0; dp < 2; ++dp)
      #pragma unroll
      for (int mt = 0; mt < 4; ++mt)
        #pragma unroll
        for (int nt = 0; nt < 2; ++nt)
          acc[dp][mt][nt] = (f32x4){0.f, 0.f, 0.f, 0.f};

    __syncthreads();
    // re-zero w-halo (transpose clobbered it) + stage interior
    for (int e = tid; e < 4*6*2*32; e += 256){
      int ch = e & 31; int side = (e >> 5) & 1; int r = (e >> 6) % 6; int sl = (e >> 6) / 6;
      at[sl][r][side ? 33 : 0][ch] = __float2bfloat16(0.f);
    }
    for (int j = wv; j < 24; j += 4){
      int sl = j / 6, r = j - sl*6;
      int dd = d - 1 + sl, hh = h0 - 1 + r;
      if (dd >= 0 && dd < D_ && hh >= 0 && hh < H_){
        const bf16* rowp = X1 + (((size_t)b*D_ + dd)*H_ + hh)*W_*32 + cq*8;
        #pragma unroll
        for (int half = 0; half < 2; ++half)
          gl_lds16(rowp + (size_t)(wlane + half*16)*32, &at[sl][r][1 + half*16][0]);
      } else {
        short8 z = {0,0,0,0,0,0,0,0};
        #pragma unroll
        for (int half = 0; half < 2; ++half)
          *(short8*)(&at[sl][r][1 + half*16][0] + (size_t)lane*8) = z;
      }
    }
    __syncthreads();

    #pragma unroll
    for (int kd = 0; kd < 3; ++kd)
      #pragma unroll
      for (int kh = 0; kh < 3; ++kh)
        #pragma unroll
        for (int kw = 0; kw < 3; ++kw){
          const bf16* wb = WB + (size_t)((kd*3 + kh)*3 + kw)*64*32 + quad*8;
          short8 afw[4];
          #pragma unroll
          for (int mt = 0; mt < 4; ++mt)
            afw[mt] = *(const short8*)(wb + (mt*16 + l15)*32);
          #pragma unroll
          for (int dp = 0; dp < 2; ++dp){
            short8 bfa[2];
            #pragma unroll
            for (int nt = 0; nt < 2; ++nt)
              bfa[nt] = *(const short8*)&at[dp + kd][wv + kh][nt*16 + l15 + kw][quad*8];
            #pragma unroll
            for (int mt = 0; mt < 4; ++mt)
              #pragma unroll
              for (int nt = 0; nt < 2; ++nt)
                acc[dp][mt][nt] = __builtin_amdgcn_mfma_f32_16x16x32_bf16(afw[mt], bfa[nt], acc[dp][mt][nt], 0, 0, 0);
          }
        }

    // --- transposed epilogue ---
    __syncthreads();   // all waves done reading at[] for MFMA before overwrite
    #pragma unroll
    for (int dp = 0; dp < 2; ++dp)
      #pragma unroll
      for (int nt = 0; nt < 2; ++nt)
        #pragma unroll
        for (int mt = 0; mt < 4; ++mt){
          bf16 r4[4];
          #pragma unroll
          for (int rg = 0; rg < 4; ++rg){
            float y = acc[dp][mt][nt][rg] + br[mt][rg];
            psum[mt][rg] += y;
            psq[mt][rg]  = fmaf(y, y, psq[mt][rg]);
            r4[rg] = __float2bfloat16(y);
          }
          *(short4v*)&tb[(size_t)(dp*32 + nt*16 + l15)*72 + mt*16 + quad*4] = *(short4v*)r4;
        }
    __syncthreads();   // tb visible (also orders vs other waves' staging next pair)
    #pragma unroll
    for (int dp = 0; dp < 2; ++dp){
      const size_t rowbase = (((size_t)b*D_ + (d + dp))*H_ + (h0 + wv))*W_;
      #pragma unroll
      for (int j = 0; j < 4; ++j){
        int flat = j*64 + lane;       // 16B-chunk id in [0,256)
        int w  = flat >> 3;           // 0..31
        int o8 = flat & 7;            // which 16B of the 128B pixel row
        short8 v = *(short8*)&tb[(size_t)(dp*32 + w)*72 + o8*8];
        *(short8*)&X2[(rowbase + w)*64 + o8*8] = v;
      }
    }
  }

  // BN2 stats: reduce across l15, bucketed atomics from l15==0
  #pragma unroll
  for (int mt = 0; mt < 4; ++mt)
    #pragma unroll
    for (int rg = 0; rg < 4; ++rg){
      float s1 = psum[mt][rg], s2 = psq[mt][rg];
      #pragma unroll
      for (int m = 1; m < 16; m <<= 1){
        s1 += __shfl_xor(s1, m, 64);
        s2 += __shfl_xor(s2, m, 64);
      }
      if (l15 == 0){
        int o = mt*16 + quad*4 + rg;
        atomicAdd(&stats[bucket*128 + o], s1);
        atomicAdd(&stats[bucket*128 + 64 + o], s2);
      }
    }
}

// ---------------- in-place BN+ReLU on channel-last tensor ----------------

template<int C>
__global__ void bnact_kernel(bf16* __restrict__ x, const float* __restrict__ ss){
  size_t i8 = (size_t)blockIdx.x*blockDim.x + threadIdx.x;
  if (i8 >= (size_t)B_*DHW_*(C/8)) return;
  int ob = ((int)(i8 & (C/8 - 1))) * 8;
  bf16* p = x + i8*8;
  short8 v = *(short8*)p;
  bf16* pv = (bf16*)&v;
  #pragma unroll
  for (int j = 0; j < 8; ++j){
    int o = ob + j;
    float f = fmaxf(fmaf(ss[o], __bfloat162float(pv[j]), ss[C + o]), 0.f);
    pv[j] = __float2bfloat16(f);
  }
  *(short8*)p = v;
}

// ---------------- conv3 MFMA: + BN3 stats + min/max over d ----------------

template<int DCHUNK>
__global__ __launch_bounds__(256, 2)
void conv3mfma_kernel(const bf16* __restrict__ X, const bf16* __restrict__ WB,
                      const float* __restrict__ bias, float* __restrict__ stats,
                      bf16* __restrict__ minp, bf16* __restrict__ maxp){
  const int tid  = threadIdx.x;
  const int lane = tid & 63;
  const int wv   = tid >> 6;
  const int l15  = lane & 15;
  const int quad = lane >> 4;
  const int h0   = blockIdx.x * 4;
  const int d0   = blockIdx.y * DCHUNK;
  const int b    = blockIdx.z;
  const int bucket = ((int)blockIdx.x | ((int)blockIdx.y << 5)) & (NBUCK - 1);

  __shared__ __align__(16) bf16 at[4][6][34][32];

  for (int e = tid; e < 4*6*2*32; e += 256){
    int ch = e & 31; int side = (e >> 5) & 1; int r = (e >> 6) % 6; int sl = (e >> 6) / 6;
    at[sl][r][side ? 33 : 0][ch] = __float2bfloat16(0.f);
  }

  f32x4 acc[2][2][4];
  float mmx[2][4][4], mmn[2][4][4];
  float brg[4];
  #pragma unroll
  for (int nt = 0; nt < 4; ++nt) brg[nt] = bias[nt*16 + l15];
  #pragma unroll
  for (int mh = 0; mh < 2; ++mh)
    #pragma unroll
    for (int nt = 0; nt < 4; ++nt)
      #pragma unroll
      for (int rg = 0; rg < 4; ++rg){ mmx[mh][nt][rg] = -FLT_MAX; mmn[mh][nt][rg] = FLT_MAX; }
  float psum[4] = {0.f,0.f,0.f,0.f}, psq[4] = {0.f,0.f,0.f,0.f};

  const int wlane = lane >> 2;
  const int cq    = lane & 3;

  for (int p = 0; p < DCHUNK/2; ++p){
    const int d = d0 + 2*p;
    #pragma unroll
    for (int dp = 0; dp < 2; ++dp)
      #pragma unroll
      for (int mh = 0; mh < 2; ++mh)
        #pragma unroll
        for (int nt = 0; nt < 4; ++nt)
          acc[dp][mh][nt] = (f32x4){0.f, 0.f, 0.f, 0.f};

    for (int ic = 0; ic < 2; ++ic){
      __syncthreads();
      for (int j = wv; j < 24; j += 4){
        int sl = j / 6, r = j - sl*6;
        int dd = d - 1 + sl, hh = h0 - 1 + r;
        if (dd >= 0 && dd < D_ && hh >= 0 && hh < H_){
          const bf16* rowp = X + (((size_t)b*D_ + dd)*H_ + hh)*W_*64 + ic*32 + cq*8;
          #pragma unroll
          for (int half = 0; half < 2; ++half)
            gl_lds16(rowp + (size_t)(wlane + half*16)*64, &at[sl][r][1 + half*16][0]);
        } else {
          short8 z = {0,0,0,0,0,0,0,0};
          #pragma unroll
          for (int half = 0; half < 2; ++half)
            *(short8*)(&at[sl][r][1 + half*16][0] + (size_t)lane*8) = z;
        }
      }
      __syncthreads();

      #pragma unroll
      for (int kd = 0; kd < 3; ++kd)
        #pragma unroll
        for (int kh = 0; kh < 3; ++kh)
          #pragma unroll
          for (int kw = 0; kw < 3; ++kw){
            const bf16* wb = WB + (size_t)((kd*3 + kh)*3 + kw)*64*64 + ic*32 + quad*8;
            short8 bfr[4];
            #pragma unroll
            for (int nt = 0; nt < 4; ++nt)
              bfr[nt] = *(const short8*)(wb + (nt*16 + l15)*64);
            #pragma unroll
            for (int dp = 0; dp < 2; ++dp){
              short8 af[2];
              #pragma unroll
              for (int mh = 0; mh < 2; ++mh)
                af[mh] = *(const short8*)&at[dp + kd][wv + kh][mh*16 + l15 + kw][quad*8];
              #pragma unroll
              for (int mh = 0; mh < 2; ++mh)
                #pragma unroll
                for (int nt = 0; nt < 4; ++nt)
                  acc[dp][mh][nt] = __builtin_amdgcn_mfma_f32_16x16x32_bf16(af[mh], bfr[nt], acc[dp][mh][nt], 0, 0, 0);
            }
          }
    }

    #pragma unroll
    for (int dp = 0; dp < 2; ++dp)
      #pragma unroll
      for (int mh = 0; mh < 2; ++mh)
        #pragma unroll
        for (int nt = 0; nt < 4; ++nt)
          #pragma unroll
          for (int rg = 0; rg < 4; ++rg){
            float y = acc[dp][mh][nt][rg] + brg[nt];
            psum[nt] += y;
            psq[nt]  = fmaf(y, y, psq[nt]);
            mmx[mh][nt][rg] = fmaxf(mmx[mh][nt][rg], y);
            mmn[mh][nt][rg] = fminf(mmn[mh][nt][rg], y);
          }
  }

  #pragma unroll
  for (int nt = 0; nt < 4; ++nt){
    float s1 = psum[nt], s2 = psq[nt];
    s1 += __shfl_xor(s1, 16, 64);  s2 += __shfl_xor(s2, 16, 64);
    s1 += __shfl_xor(s1, 32, 64);  s2 += __shfl_xor(s2, 32, 64);
    if (quad == 0){
      atomicAdd(&stats[bucket*128 + nt*16 + l15], s1);
      atomicAdd(&stats[bucket*128 + 64 + nt*16 + l15], s2);
    }
  }

  const size_t slab = (size_t)blockIdx.y * OUTN_;
  const int h = h0 + wv;
  #pragma unroll
  for (int mh = 0; mh < 2; ++mh)
    #pragma unroll
    for (int nt = 0; nt < 4; ++nt){
      int o = nt*16 + l15;
      #pragma unroll
      for (int rg = 0; rg < 4; ++rg){
        int w = mh*16 + quad*4 + rg;
        size_t idx = slab + ((size_t)(b*64 + o))*HW_ + h*W_ + w;
        maxp[idx] = __float2bfloat16(mmx[mh][nt][rg]);
        minp[idx] = __float2bfloat16(mmn[mh][nt][rg]);
      }
    }
}

// ---------------- final: reduce slabs, apply BN3+ReLU via monotonicity ----------------

__global__ void bevreduce_kernel(const bf16* __restrict__ minp, const bf16* __restrict__ maxp,
                                 const float* __restrict__ ss, float* __restrict__ out, int nslab){
  int j = blockIdx.x*blockDim.x + threadIdx.x;
  if (j >= OUTN_) return;
  int o = (j >> 12) & 63;
  float mx = -FLT_MAX, mn = FLT_MAX;
  for (int s = 0; s < nslab; ++s){
    mx = fmaxf(mx, __bfloat162float(maxp[(size_t)s*OUTN_ + j]));
    mn = fminf(mn, __bfloat162float(minp[(size_t)s*OUTN_ + j]));
  }
  float a = ss[o], sh = ss[64 + o];
  float v = (a >= 0.f) ? mx : mn;   // relu(a*z+s) monotone in z, direction sign(a)
  out[j] = fmaxf(fmaf(a, v, sh), 0.f);
}

// ---------------- BN finalize: sum buckets, scale/shift ----------------

__global__ void finalize_kernel(const float* __restrict__ stb, const float* __restrict__ gamma,
                                const float* __restrict__ beta, float* __restrict__ ss, int C){
  int c = threadIdx.x;
  if (c >= C) return;
  float s1 = 0.f, s2 = 0.f;
  for (int k = 0; k < NBUCK; ++k){
    s1 += stb[k*128 + c];
    s2 += stb[k*128 + C + c];
  }
  const float invCnt = 1.0f / (float)((size_t)B_*DHW_);
  float mean = s1 * invCnt;
  float var  = s2 * invCnt - mean*mean;
  float a = gamma[c] * rsqrtf(var + EPSV);
  ss[c]     = a;
  ss[C + c] = beta[c] - mean*a;
}

// ---------------- launch ----------------

extern "C" void kernel_launch(void* const* d_in, const int* in_sizes, int n_in,
                              void* d_out, int out_size, void* d_ws, size_t ws_size,
                              hipStream_t stream){
  const float* pc  = (const float*)d_in[0];
  const float* w1  = (const float*)d_in[1];
  const float* b1  = (const float*)d_in[2];
  const float* g1  = (const float*)d_in[3];
  const float* be1 = (const float*)d_in[4];
  const float* w2  = (const float*)d_in[5];
  const float* b2  = (const float*)d_in[6];
  const float* g2  = (const float*)d_in[7];
  const float* be2 = (const float*)d_in[8];
  const float* w3  = (const float*)d_in[9];
  const float* b3  = (const float*)d_in[10];
  const float* g3  = (const float*)d_in[11];
  const float* be3 = (const float*)d_in[12];
  const int N = in_sizes[0] / 6;  // (B=2, 3, N)
  float* out = (float*)d_out;

  char* wsb = (char*)d_ws;
  size_t off = 0;
  auto alloc = [&](size_t bytes)->char*{
    off = (off + 255) & ~(size_t)255;
    char* p = wsb + off; off += bytes; return p;
  };
  float* g0   = (float*)alloc((size_t)B_*DHW_*4);   // 4 MB
  float* wr1  = (float*)alloc(864*4);               // [27k][32o] fp32
  float* wr2  = (float*)alloc(55296*4);             // fp32 (fallback fused12)
  bf16*  wr2b = (bf16*) alloc(55296*2);             // [tap][64o][32i] bf16
  bf16*  wr3b = (bf16*) alloc(110592*2);            // [tap][64o][64i] bf16
  float* mins = (float*)alloc(8*4);
  float* stb  = (float*)alloc((size_t)3*NBUCK*128*4); // bucketed stats, 192 KB
  float* ss   = (float*)alloc(3*128*4);

  constexpr int DCHUNK = 8;
  constexpr int NSLAB  = D_ / DCHUNK;               // 16
  const size_t SX1  = (size_t)B_*DHW_*32*2;         // 64 MiB channel-last bf16
  const size_t SX2  = (size_t)B_*DHW_*64*2;         // 128 MiB channel-last bf16
  const size_t SMM  = (size_t)NSLAB*OUTN_*2;        // 16 MiB per min/max array

  // regionR: x1 (64MiB) aliases minp/maxp (32MiB) — disjoint lifetimes
  const size_t prefixEnd = (off + 255) & ~(size_t)255;
  const bool useMfma2 = ws_size >= prefixEnd + SX1 + SX2 + 1024;

  char* regionR = alloc(useMfma2 ? SX1 : 2*SMM);
  bf16* maxp = (bf16*)regionR;
  bf16* minp = (bf16*)(regionR + SMM);
  bf16* x1   = (bf16*)regionR;
  bf16* x2   = (bf16*)alloc(SX2);

  float* st1 = stb;
  float* st2 = stb + (size_t)NBUCK*128;
  float* st3 = stb + (size_t)2*NBUCK*128;

  // prologue
  zero_kernel<<<(B_*DHW_ + 255)/256, 256, 0, stream>>>(g0, B_*DHW_);
  zero_kernel<<<(3*NBUCK*128 + 255)/256, 256, 0, stream>>>(stb, 3*NBUCK*128);
  min_kernel<<<B_*3, 256, 0, stream>>>(pc, mins, N);
  scatter_kernel<<<(B_*N + 255)/256, 256, 0, stream>>>(pc, mins, g0, N);
  reorder_kernel<<<(864 + 255)/256, 256, 0, stream>>>(w1, wr1, 1, 32);
  reorder_kernel<<<(55296 + 255)/256, 256, 0, stream>>>(w2, wr2, 32, 64);
  reorder2b_kernel<<<(55296 + 255)/256, 256, 0, stream>>>(w2, wr2b);
  reorder3b_kernel<<<(110592 + 255)/256, 256, 0, stream>>>(w3, wr3b);

  dim3 cgrid(16, 128, 2);                           // (8h-tiles, d, b)
  dim3 mgrid(32, NSLAB, 2);                         // (4h-tiles, d-slabs, b) = 1024 blocks

  if (useMfma2){
    conv1act_kernel<<<cgrid, 256, 0, stream>>>(g0, wr1, b1, x1, st1);
    finalize_kernel<<<1, 64, 0, stream>>>(st1, g1, be1, ss, 32);
    bnact_kernel<32><<<(int)(((size_t)B_*DHW_*4 + 255)/256), 256, 0, stream>>>(x1, ss);
    conv2mfma_kernel<DCHUNK><<<mgrid, 256, 0, stream>>>(x1, wr2b, b2, x2, st2);
  } else {
    convstats_kernel<<<cgrid, 256, 0, stream>>>(g0, wr1, b1, st1);
    finalize_kernel<<<1, 64, 0, stream>>>(st1, g1, be1, ss, 32);
    fused12_kernel<<<cgrid, 256, 0, stream>>>(g0, wr1, b1, ss, wr2, b2, x2, st2);
  }
  finalize_kernel<<<1, 64, 0, stream>>>(st2, g2, be2, ss + 128, 64);

  bnact_kernel<64><<<(int)(((size_t)B_*DHW_*8 + 255)/256), 256, 0, stream>>>(x2, ss + 128);

  conv3mfma_kernel<DCHUNK><<<mgrid, 256, 0, stream>>>(x2, wr3b, b3, st3, minp, maxp);
  finalize_kernel<<<1, 64, 0, stream>>>(st3, g3, be3, ss + 256, 64);
  bevreduce_kernel<<<(OUTN_ + 255)/256, 256, 0, stream>>>(minp, maxp, ss + 256, out, NSLAB);
}

// Round 12
// 1364.236 us; speedup vs baseline: 1.0820x; 1.0820x over previous
//
#include <hip/hip_runtime.h>
#include <hip/hip_bf16.h>
#include <float.h>

// LiDAR BEV pipeline (fp32 I/O):
//   voxelize -> conv3d(1->32)+BN+ReLU -> conv3d(32->64)+BN+ReLU -> conv3d(64->64)+BN+ReLU -> max over D
// R11 post-mortem: transposed stores made WRITE worse; root cause re-diagnosed as per-XCD
// L2 thrash (round-robin block->XCD scatters co-resident blocks; halo window ~15MB >> 4MiB L2
// -> 3-4x read amplification + RMW write amplification). R12: revert to R10 conv kernels
// (DCHUNK=16, direct 8B stores) + XCD-locality swizzle (each XCD owns a contiguous h x d
// region) + fold BN+ReLU into MFMA staging (in-LDS transform; bnact dispatches deleted).

#define VOXEL 0.0625f
#define D_ 128
#define H_ 128
#define W_ 32
#define HW_ (H_*W_)      // 4096
#define DHW_ (D_*H_*W_)  // 524288
#define B_ 2
#define EPSV 1e-5f
#define OUTN_ (B_*64*HW_) // 524288
#define NBUCK 128         // stats buckets

typedef __hip_bfloat16 bf16;
typedef __attribute__((ext_vector_type(8))) short short8;   // 8 bf16
typedef __attribute__((ext_vector_type(4))) short short4v;  // 4 bf16
typedef __attribute__((ext_vector_type(4))) float f32x4;

__device__ inline void gl_lds16(const void* g, void* l){
  // async global->LDS, 16B per lane; LDS dest = base + lane*16 (wave-uniform base)
  __builtin_amdgcn_global_load_lds(
      (const __attribute__((address_space(1))) unsigned int*)g,
      (__attribute__((address_space(3))) unsigned int*)l, 16, 0, 0);
}

// XCD-locality swizzle: launch grid (32, NS, B_); assume XCD = flat_id % 8 (round-robin).
// Remap so each XCD owns a contiguous block range (shared halos stay in its 4MiB L2).
__device__ inline void swizzle_blocks(int NS, int& hb, int& slab, int& b){
  int flat = (int)blockIdx.x + 32*((int)blockIdx.y + NS*(int)blockIdx.z);
  int nper = (32*NS*B_) >> 3;
  int xcd = flat & 7, j = flat >> 3;
  int f = xcd*nper + j;
  hb   = f & 31;
  slab = (f >> 5) % NS;
  b    = f / (32*NS);
}

// ---------------- init ----------------

__global__ void zero_kernel(float* __restrict__ p, int n){
  int i = blockIdx.x*blockDim.x + threadIdx.x;
  if (i < n) p[i] = 0.f;
}

// ---------------- voxelize ----------------

__global__ void min_kernel(const float* __restrict__ pc, float* __restrict__ mins, int N){
  const float* base = pc + (size_t)blockIdx.x * N;
  float m = FLT_MAX;
  for (int j = threadIdx.x; j < N; j += blockDim.x){
    float v = base[j];
    if (v != v) v = 0.f;          // NaN -> 0, matching reference
    m = fminf(m, v);
  }
  for (int off = 32; off > 0; off >>= 1)
    m = fminf(m, __shfl_xor(m, off, 64));
  __shared__ float red[4];
  int wave = threadIdx.x >> 6;
  if ((threadIdx.x & 63) == 0) red[wave] = m;
  __syncthreads();
  if (threadIdx.x == 0){
    float r = red[0];
    for (int k = 1; k < (int)(blockDim.x >> 6); ++k) r = fminf(r, red[k]);
    mins[blockIdx.x] = r;
  }
}

__global__ void scatter_kernel(const float* __restrict__ pc, const float* __restrict__ mins,
                               float* __restrict__ grid, int N){
  int idx = blockIdx.x*blockDim.x + threadIdx.x;
  if (idx >= B_*N) return;
  int b = idx / N, n = idx - b*N;
  float x = pc[((size_t)b*3 + 0)*N + n];
  float y = pc[((size_t)b*3 + 1)*N + n];
  float z = pc[((size_t)b*3 + 2)*N + n];
  if (x != x) x = 0.f;
  if (y != y) y = 0.f;
  if (z != z) z = 0.f;
  int ix = (int)floorf((x - mins[b*3+0]) / VOXEL);
  int iy = (int)floorf((y - mins[b*3+1]) / VOXEL);
  int iz = (int)floorf((z - mins[b*3+2]) / VOXEL);
  ix = min(max(ix, 0), D_-1);
  iy = min(max(iy, 0), H_-1);
  iz = min(max(iz, 0), W_-1);
  grid[(size_t)b*DHW_ + (size_t)ix*HW_ + iy*W_ + iz] = 1.0f;
}

// ---------------- weight reorders ----------------

__global__ void reorder_kernel(const float* __restrict__ w, float* __restrict__ wr, int CIN, int COUT){
  int idx = blockIdx.x*blockDim.x + threadIdx.x;
  int total = COUT*CIN*27;
  if (idx >= total) return;
  int o = idx / (CIN*27);
  int rem = idx - o*(CIN*27);
  int i = rem / 27;
  int k = rem - i*27;
  wr[(i*27 + k)*COUT + o] = w[idx];
}

// w3 (64,64,3,3,3) fp32 -> [tap][o][64 i] bf16
__global__ void reorder3b_kernel(const float* __restrict__ w, bf16* __restrict__ wb){
  int idx = blockIdx.x*blockDim.x + threadIdx.x;
  if (idx >= 64*64*27) return;
  int o = idx / (64*27);
  int rem = idx - o*(64*27);
  int i = rem / 27;
  int tap = rem - i*27;
  wb[((size_t)tap*64 + o)*64 + i] = __float2bfloat16(w[idx]);
}

// w2 (64,32,3,3,3) fp32 -> [tap][o][32 i] bf16
__global__ void reorder2b_kernel(const float* __restrict__ w, bf16* __restrict__ wb){
  int idx = blockIdx.x*blockDim.x + threadIdx.x;
  if (idx >= 64*32*27) return;
  int o = idx / (32*27);
  int rem = idx - o*(32*27);
  int i = rem / 27;
  int tap = rem - i*27;
  wb[((size_t)tap*64 + o)*32 + i] = __float2bfloat16(w[idx]);
}

// ---------------- fp32 conv inner (conv1-class kernels) ----------------

template<int HT, int OPT, int COUT>
__device__ inline void conv_inner(float (*xs)[HT+2][34], float (*wsm)[COUT],
                                  int w, int og, float (*acc)[OPT]){
  #pragma unroll
  for (int kd = 0; kd < 3; ++kd){
    float xr[HT+2][3];
    #pragma unroll
    for (int r = 0; r < HT+2; ++r)
      #pragma unroll
      for (int c = 0; c < 3; ++c)
        xr[r][c] = xs[kd][r][w + c];
    #pragma unroll
    for (int kh = 0; kh < 3; ++kh)
      #pragma unroll
      for (int kw = 0; kw < 3; ++kw){
        const float* wp = &wsm[kd*9 + kh*3 + kw][og*OPT];
        float wv[OPT];
        #pragma unroll
        for (int oo = 0; oo < OPT; ++oo) wv[oo] = wp[oo];
        #pragma unroll
        for (int h = 0; h < HT; ++h){
          float xv = xr[h + kh][kw];
          #pragma unroll
          for (int oo = 0; oo < OPT; ++oo)
            acc[h][oo] = fmaf(xv, wv[oo], acc[h][oo]);
        }
      }
  }
}

// ---------------- conv1 BN stats only (fallback path) ----------------

__global__ __launch_bounds__(256)
void convstats_kernel(const float* __restrict__ X, const float* __restrict__ WR,
                      const float* __restrict__ bias, float* __restrict__ stats){
  const int tid = threadIdx.x;
  const int w   = tid & 31;
  const int og  = tid >> 5;
  const int h0  = blockIdx.x * 8;
  const int d   = blockIdx.y;
  const int b   = blockIdx.z;
  const int bucket = d & (NBUCK - 1);

  __shared__ float xs[3][10][34];
  __shared__ float wsm[27][32];

  float acc[8][4];
  #pragma unroll
  for (int h = 0; h < 8; ++h)
    #pragma unroll
    for (int oo = 0; oo < 4; ++oo) acc[h][oo] = 0.f;

  for (int e = tid; e < 27*32; e += 256)
    ((float*)wsm)[e] = WR[e];
  for (int e = tid; e < 960; e += 256){
    int ds = e / 320; int rem = e - ds*320; int r = rem >> 5; int ww = rem & 31;
    int dd = d + ds - 1, hh = h0 + r - 1;
    float v = 0.f;
    if (dd >= 0 && dd < D_ && hh >= 0 && hh < H_)
      v = X[((size_t)b*D_ + dd)*HW_ + hh*W_ + ww];
    xs[ds][r][ww + 1] = v;
  }
  if (tid < 30){ int ds = tid/10, r = tid - ds*10; xs[ds][r][0] = 0.f; xs[ds][r][33] = 0.f; }
  __syncthreads();
  conv_inner<8, 4, 32>(xs, wsm, w, og, acc);

  #pragma unroll
  for (int oo = 0; oo < 4; ++oo){
    int o = og*4 + oo;
    float bo = bias[o];
    float s1 = 0.f, s2 = 0.f;
    #pragma unroll
    for (int h = 0; h < 8; ++h){
      float y = acc[h][oo] + bo;
      s1 += y;
      s2 = fmaf(y, y, s2);
    }
    for (int m = 16; m > 0; m >>= 1){
      s1 += __shfl_xor(s1, m, 32);
      s2 += __shfl_xor(s2, m, 32);
    }
    if (w == 0){
      atomicAdd(&stats[bucket*128 + o], s1);
      atomicAdd(&stats[bucket*128 + 32 + o], s2);
    }
  }
}

// ---------------- conv1 -> RAW x1 channel-last bf16 [b][d][h][w][32] + BN1 stats ----------------

__global__ __launch_bounds__(256)
void conv1act_kernel(const float* __restrict__ X, const float* __restrict__ WR,
                     const float* __restrict__ bias, bf16* __restrict__ X1,
                     float* __restrict__ stats){
  const int tid = threadIdx.x;
  const int w   = tid & 31;
  const int og  = tid >> 5;
  const int h0  = blockIdx.x * 8;
  const int d   = blockIdx.y;
  const int b   = blockIdx.z;
  const int bucket = d & (NBUCK - 1);

  __shared__ float xs[3][10][34];
  __shared__ float wsm[27][32];

  float acc[8][4];
  #pragma unroll
  for (int h = 0; h < 8; ++h)
    #pragma unroll
    for (int oo = 0; oo < 4; ++oo) acc[h][oo] = 0.f;

  for (int e = tid; e < 27*32; e += 256)
    ((float*)wsm)[e] = WR[e];
  for (int e = tid; e < 960; e += 256){
    int ds = e / 320; int rem = e - ds*320; int r = rem >> 5; int ww = rem & 31;
    int dd = d + ds - 1, hh = h0 + r - 1;
    float v = 0.f;
    if (dd >= 0 && dd < D_ && hh >= 0 && hh < H_)
      v = X[((size_t)b*D_ + dd)*HW_ + hh*W_ + ww];
    xs[ds][r][ww + 1] = v;
  }
  if (tid < 30){ int ds = tid/10, r = tid - ds*10; xs[ds][r][0] = 0.f; xs[ds][r][33] = 0.f; }
  __syncthreads();
  conv_inner<8, 4, 32>(xs, wsm, w, og, acc);

  float bo[4], psum[4], psq[4];
  #pragma unroll
  for (int oo = 0; oo < 4; ++oo){
    bo[oo] = bias[og*4 + oo]; psum[oo] = 0.f; psq[oo] = 0.f;
  }
  #pragma unroll
  for (int h = 0; h < 8; ++h){
    bf16 row[4];
    #pragma unroll
    for (int oo = 0; oo < 4; ++oo){
      float y = acc[h][oo] + bo[oo];
      row[oo] = __float2bfloat16(y);
      psum[oo] += y;
      psq[oo]  = fmaf(y, y, psq[oo]);
    }
    *(short4v*)&X1[((((size_t)b*D_ + d)*H_ + (h0 + h))*W_ + w)*32 + og*4] = *(short4v*)row;
  }
  #pragma unroll
  for (int oo = 0; oo < 4; ++oo){
    float s1 = psum[oo], s2 = psq[oo];
    for (int m = 16; m > 0; m >>= 1){
      s1 += __shfl_xor(s1, m, 32);
      s2 += __shfl_xor(s2, m, 32);
    }
    if (w == 0){
      int o = og*4 + oo;
      atomicAdd(&stats[bucket*128 + o], s1);
      atomicAdd(&stats[bucket*128 + 32 + o], s2);
    }
  }
}

// ---------------- fused12 (fp32 fallback path, writes raw x2 + BN2 stats) ----------------

__global__ __launch_bounds__(256)
void fused12_kernel(const float* __restrict__ G0, const float* __restrict__ WR1,
                    const float* __restrict__ B1, const float* __restrict__ SS1,
                    const float* __restrict__ WR2, const float* __restrict__ B2,
                    bf16* __restrict__ X2, float* __restrict__ stats){
  const int tid = threadIdx.x;
  const int w   = tid & 31;
  const int og  = tid >> 5;
  const int h0  = blockIdx.x * 8;
  const int d   = blockIdx.y;
  const int b   = blockIdx.z;
  const int bucket = d & (NBUCK - 1);

  __shared__ float gs[5][12][34];
  __shared__ float w1s[32][27];
  __shared__ float xs[3][10][34];
  __shared__ float wsm[27][64];

  for (int e = tid; e < 5*12*34; e += 256){
    int ds = e / 408; int rem = e - ds*408; int r = rem / 34; int c = rem - r*34;
    int dd = d - 2 + ds, hh = h0 - 2 + r, ww = c - 1;
    float v = 0.f;
    if (c >= 1 && c <= 32 && dd >= 0 && dd < D_ && hh >= 0 && hh < H_)
      v = G0[((size_t)b*D_ + dd)*HW_ + hh*W_ + ww];
    gs[ds][r][c] = v;
  }
  for (int e = tid; e < 864; e += 256){
    int i = e/27, k = e - 27*i;
    w1s[i][k] = WR1[k*32 + i];
  }

  float acc[8][8];
  #pragma unroll
  for (int h = 0; h < 8; ++h)
    #pragma unroll
    for (int oo = 0; oo < 8; ++oo) acc[h][oo] = 0.f;

  for (int i = 0; i < 32; ++i){
    __syncthreads();
    float a1 = SS1[i];
    float f1 = fmaf(a1, B1[i], SS1[32 + i]);
    for (int e = tid; e < 1020; e += 256){
      int ds = e / 340; int rem = e - ds*340; int r = rem / 34; int c = rem - r*34;
      float v = 0.f;
      int dd = d - 1 + ds, hh = h0 - 1 + r;
      if (c >= 1 && c <= 32 && dd >= 0 && dd < D_ && hh >= 0 && hh < H_){
        float s = 0.f;
        #pragma unroll
        for (int kd = 0; kd < 3; ++kd)
          #pragma unroll
          for (int kh = 0; kh < 3; ++kh)
            #pragma unroll
            for (int kw = 0; kw < 3; ++kw)
              s = fmaf(gs[ds+kd][r+kh][c-1+kw], w1s[i][kd*9+kh*3+kw], s);
        v = fmaxf(fmaf(a1, s, f1), 0.f);
      }
      xs[ds][r][c] = v;
    }
    for (int e = tid; e < 27*64; e += 256)
      ((float*)wsm)[e] = WR2[i*27*64 + e];
    __syncthreads();
    conv_inner<8, 8, 64>(xs, wsm, w, og, acc);
  }

  float bo[8], psum[8], psq[8];
  #pragma unroll
  for (int oo = 0; oo < 8; ++oo){ bo[oo] = B2[og*8 + oo]; psum[oo] = 0.f; psq[oo] = 0.f; }
  #pragma unroll
  for (int h = 0; h < 8; ++h){
    bf16 row[8];
    #pragma unroll
    for (int oo = 0; oo < 8; ++oo){
      float y = acc[h][oo] + bo[oo];
      row[oo] = __float2bfloat16(y);
      psum[oo] += y;
      psq[oo]  = fmaf(y, y, psq[oo]);
    }
    *(short8*)&X2[((((size_t)b*D_ + d)*H_ + (h0 + h))*W_ + w)*64 + og*8] = *(short8*)row;
  }
  #pragma unroll
  for (int oo = 0; oo < 8; ++oo){
    float s1 = psum[oo], s2 = psq[oo];
    for (int m = 16; m > 0; m >>= 1){
      s1 += __shfl_xor(s1, m, 32);
      s2 += __shfl_xor(s2, m, 32);
    }
    if (w == 0){
      atomicAdd(&stats[bucket*128 + og*8 + oo], s1);
      atomicAdd(&stats[bucket*128 + 64 + og*8 + oo], s2);
    }
  }
}

// ---------------- in-LDS BN+ReLU transform of a staged tile (padding cells stay 0) ----------------
// tile at[4][6][34][32], staged channels = chbase..chbase+31; sA/sS indexed by global channel.

__device__ inline void tile_bnact(bf16 (*at)[6][34][32], const float* sA, const float* sS,
                                  int chbase, int d, int h0, int tid){
  for (int e = tid; e < 4*6*32*4; e += 256){
    int c8 = e & 3;
    int w  = (e >> 2) & 31;
    int r  = (e >> 7) % 6;
    int sl = (e >> 7) / 6;
    int dd = d - 1 + sl, hh = h0 - 1 + r;
    if (dd < 0 || dd >= D_ || hh < 0 || hh >= H_) continue;   // OOB rows stay zero
    bf16* p = &at[sl][r][w + 1][c8*8];
    short8 v = *(short8*)p;
    bf16* pv = (bf16*)&v;
    #pragma unroll
    for (int t = 0; t < 8; ++t){
      int ch = chbase + c8*8 + t;
      pv[t] = __float2bfloat16(fmaxf(fmaf(sA[ch], __bfloat162float(pv[t]), sS[ch]), 0.f));
    }
    *(short8*)p = v;
  }
}

// ---------------- conv2 MFMA: weights=A (M=64 o), activations=B (N=32 w) ----------------
// Reads RAW x1; BN1+ReLU applied in-LDS after staging. XCD-swizzled grid.

template<int DCHUNK>
__global__ __launch_bounds__(256, 2)
void conv2mfma_kernel(const bf16* __restrict__ X1, const bf16* __restrict__ WB,
                      const float* __restrict__ SS1, const float* __restrict__ B2,
                      bf16* __restrict__ X2, float* __restrict__ stats){
  const int tid  = threadIdx.x;
  const int lane = tid & 63;
  const int wv   = tid >> 6;        // wave id = h-row
  const int l15  = lane & 15;
  const int quad = lane >> 4;
  constexpr int NS = D_ / DCHUNK;
  int hb, slab, b;
  swizzle_blocks(NS, hb, slab, b);
  const int h0 = hb * 4;
  const int d0 = slab * DCHUNK;
  const int bucket = (hb | (slab << 5)) & (NBUCK - 1);

  __shared__ __align__(16) bf16 at[4][6][34][32];   // 52,224 B
  __shared__ float sA[32], sS[32];

  if (tid < 32){ sA[tid] = SS1[tid]; sS[tid] = SS1[32 + tid]; }
  for (int e = tid; e < 4*6*2*32; e += 256){
    int ch = e & 31; int side = (e >> 5) & 1; int r = (e >> 6) % 6; int sl = (e >> 6) / 6;
    at[sl][r][side ? 33 : 0][ch] = __float2bfloat16(0.f);
  }

  f32x4 acc[2][4][2];               // [dp][mt][nt]
  float br[4][4], psum[4][4], psq[4][4];
  #pragma unroll
  for (int mt = 0; mt < 4; ++mt)
    #pragma unroll
    for (int rg = 0; rg < 4; ++rg){
      br[mt][rg] = B2[mt*16 + quad*4 + rg];
      psum[mt][rg] = 0.f; psq[mt][rg] = 0.f;
    }

  const int wlane = lane >> 2;
  const int cq    = lane & 3;

  for (int p = 0; p < DCHUNK/2; ++p){
    const int d = d0 + 2*p;
    #pragma unroll
    for (int dp = 0; dp < 2; ++dp)
      #pragma unroll
      for (int mt = 0; mt < 4; ++mt)
        #pragma unroll
        for (int nt = 0; nt < 2; ++nt)
          acc[dp][mt][nt] = (f32x4){0.f, 0.f, 0.f, 0.f};

    __syncthreads();
    for (int j = wv; j < 24; j += 4){
      int sl = j / 6, r = j - sl*6;
      int dd = d - 1 + sl, hh = h0 - 1 + r;
      if (dd >= 0 && dd < D_ && hh >= 0 && hh < H_){
        const bf16* rowp = X1 + (((size_t)b*D_ + dd)*H_ + hh)*W_*32 + cq*8;
        #pragma unroll
        for (int half = 0; half < 2; ++half)
          gl_lds16(rowp + (size_t)(wlane + half*16)*32, &at[sl][r][1 + half*16][0]);
      } else {
        short8 z = {0,0,0,0,0,0,0,0};
        #pragma unroll
        for (int half = 0; half < 2; ++half)
          *(short8*)(&at[sl][r][1 + half*16][0] + (size_t)lane*8) = z;
      }
    }
    __syncthreads();
    tile_bnact(at, sA, sS, 0, d, h0, tid);   // BN1+ReLU in LDS
    __syncthreads();

    #pragma unroll
    for (int kd = 0; kd < 3; ++kd)
      #pragma unroll
      for (int kh = 0; kh < 3; ++kh)
        #pragma unroll
        for (int kw = 0; kw < 3; ++kw){
          const bf16* wb = WB + (size_t)((kd*3 + kh)*3 + kw)*64*32 + quad*8;
          short8 afw[4];
          #pragma unroll
          for (int mt = 0; mt < 4; ++mt)
            afw[mt] = *(const short8*)(wb + (mt*16 + l15)*32);
          #pragma unroll
          for (int dp = 0; dp < 2; ++dp){
            short8 bfa[2];
            #pragma unroll
            for (int nt = 0; nt < 2; ++nt)
              bfa[nt] = *(const short8*)&at[dp + kd][wv + kh][nt*16 + l15 + kw][quad*8];
            #pragma unroll
            for (int mt = 0; mt < 4; ++mt)
              #pragma unroll
              for (int nt = 0; nt < 2; ++nt)
                acc[dp][mt][nt] = __builtin_amdgcn_mfma_f32_16x16x32_bf16(afw[mt], bfa[nt], acc[dp][mt][nt], 0, 0, 0);
          }
        }

    // pair epilogue: bias, stats, 8B stores (4 consecutive o) — R10 form
    #pragma unroll
    for (int dp = 0; dp < 2; ++dp){
      const size_t rowbase = (((size_t)b*D_ + (d + dp))*H_ + (h0 + wv))*W_;
      #pragma unroll
      for (int nt = 0; nt < 2; ++nt){
        const size_t pix = (rowbase + nt*16 + l15)*64;
        #pragma unroll
        for (int mt = 0; mt < 4; ++mt){
          bf16 row[4];
          #pragma unroll
          for (int rg = 0; rg < 4; ++rg){
            float y = acc[dp][mt][nt][rg] + br[mt][rg];
            psum[mt][rg] += y;
            psq[mt][rg]  = fmaf(y, y, psq[mt][rg]);
            row[rg] = __float2bfloat16(y);
          }
          *(short4v*)&X2[pix + mt*16 + quad*4] = *(short4v*)row;
        }
      }
    }
  }

  // BN2 stats: reduce across l15, bucketed atomics from l15==0
  #pragma unroll
  for (int mt = 0; mt < 4; ++mt)
    #pragma unroll
    for (int rg = 0; rg < 4; ++rg){
      float s1 = psum[mt][rg], s2 = psq[mt][rg];
      #pragma unroll
      for (int m = 1; m < 16; m <<= 1){
        s1 += __shfl_xor(s1, m, 64);
        s2 += __shfl_xor(s2, m, 64);
      }
      if (l15 == 0){
        int o = mt*16 + quad*4 + rg;
        atomicAdd(&stats[bucket*128 + o], s1);
        atomicAdd(&stats[bucket*128 + 64 + o], s2);
      }
    }
}

// ---------------- conv3 MFMA: reads RAW x2 (BN2+ReLU in-LDS) + BN3 stats + min/max over d ----------------

template<int DCHUNK>
__global__ __launch_bounds__(256, 2)
void conv3mfma_kernel(const bf16* __restrict__ X, const bf16* __restrict__ WB,
                      const float* __restrict__ SS2, const float* __restrict__ bias,
                      float* __restrict__ stats, bf16* __restrict__ minp, bf16* __restrict__ maxp){
  const int tid  = threadIdx.x;
  const int lane = tid & 63;
  const int wv   = tid >> 6;
  const int l15  = lane & 15;
  const int quad = lane >> 4;
  constexpr int NS = D_ / DCHUNK;
  int hb, slab, b;
  swizzle_blocks(NS, hb, slab, b);
  const int h0 = hb * 4;
  const int d0 = slab * DCHUNK;
  const int bucket = (hb | (slab << 5)) & (NBUCK - 1);

  __shared__ __align__(16) bf16 at[4][6][34][32];
  __shared__ float sA[64], sS[64];

  if (tid < 64){ sA[tid] = SS2[tid]; sS[tid] = SS2[64 + tid]; }
  for (int e = tid; e < 4*6*2*32; e += 256){
    int ch = e & 31; int side = (e >> 5) & 1; int r = (e >> 6) % 6; int sl = (e >> 6) / 6;
    at[sl][r][side ? 33 : 0][ch] = __float2bfloat16(0.f);
  }

  f32x4 acc[2][2][4];
  float mmx[2][4][4], mmn[2][4][4];
  float brg[4];
  #pragma unroll
  for (int nt = 0; nt < 4; ++nt) brg[nt] = bias[nt*16 + l15];
  #pragma unroll
  for (int mh = 0; mh < 2; ++mh)
    #pragma unroll
    for (int nt = 0; nt < 4; ++nt)
      #pragma unroll
      for (int rg = 0; rg < 4; ++rg){ mmx[mh][nt][rg] = -FLT_MAX; mmn[mh][nt][rg] = FLT_MAX; }
  float psum[4] = {0.f,0.f,0.f,0.f}, psq[4] = {0.f,0.f,0.f,0.f};

  const int wlane = lane >> 2;
  const int cq    = lane & 3;

  for (int p = 0; p < DCHUNK/2; ++p){
    const int d = d0 + 2*p;
    #pragma unroll
    for (int dp = 0; dp < 2; ++dp)
      #pragma unroll
      for (int mh = 0; mh < 2; ++mh)
        #pragma unroll
        for (int nt = 0; nt < 4; ++nt)
          acc[dp][mh][nt] = (f32x4){0.f, 0.f, 0.f, 0.f};

    for (int ic = 0; ic < 2; ++ic){
      __syncthreads();
      for (int j = wv; j < 24; j += 4){
        int sl = j / 6, r = j - sl*6;
        int dd = d - 1 + sl, hh = h0 - 1 + r;
        if (dd >= 0 && dd < D_ && hh >= 0 && hh < H_){
          const bf16* rowp = X + (((size_t)b*D_ + dd)*H_ + hh)*W_*64 + ic*32 + cq*8;
          #pragma unroll
          for (int half = 0; half < 2; ++half)
            gl_lds16(rowp + (size_t)(wlane + half*16)*64, &at[sl][r][1 + half*16][0]);
        } else {
          short8 z = {0,0,0,0,0,0,0,0};
          #pragma unroll
          for (int half = 0; half < 2; ++half)
            *(short8*)(&at[sl][r][1 + half*16][0] + (size_t)lane*8) = z;
        }
      }
      __syncthreads();
      tile_bnact(at, sA, sS, ic*32, d, h0, tid);   // BN2+ReLU in LDS
      __syncthreads();

      #pragma unroll
      for (int kd = 0; kd < 3; ++kd)
        #pragma unroll
        for (int kh = 0; kh < 3; ++kh)
          #pragma unroll
          for (int kw = 0; kw < 3; ++kw){
            const bf16* wb = WB + (size_t)((kd*3 + kh)*3 + kw)*64*64 + ic*32 + quad*8;
            short8 bfr[4];
            #pragma unroll
            for (int nt = 0; nt < 4; ++nt)
              bfr[nt] = *(const short8*)(wb + (nt*16 + l15)*64);
            #pragma unroll
            for (int dp = 0; dp < 2; ++dp){
              short8 af[2];
              #pragma unroll
              for (int mh = 0; mh < 2; ++mh)
                af[mh] = *(const short8*)&at[dp + kd][wv + kh][mh*16 + l15 + kw][quad*8];
              #pragma unroll
              for (int mh = 0; mh < 2; ++mh)
                #pragma unroll
                for (int nt = 0; nt < 4; ++nt)
                  acc[dp][mh][nt] = __builtin_amdgcn_mfma_f32_16x16x32_bf16(af[mh], bfr[nt], acc[dp][mh][nt], 0, 0, 0);
            }
          }
    }

    #pragma unroll
    for (int dp = 0; dp < 2; ++dp)
      #pragma unroll
      for (int mh = 0; mh < 2; ++mh)
        #pragma unroll
        for (int nt = 0; nt < 4; ++nt)
          #pragma unroll
          for (int rg = 0; rg < 4; ++rg){
            float y = acc[dp][mh][nt][rg] + brg[nt];
            psum[nt] += y;
            psq[nt]  = fmaf(y, y, psq[nt]);
            mmx[mh][nt][rg] = fmaxf(mmx[mh][nt][rg], y);
            mmn[mh][nt][rg] = fminf(mmn[mh][nt][rg], y);
          }
  }

  #pragma unroll
  for (int nt = 0; nt < 4; ++nt){
    float s1 = psum[nt], s2 = psq[nt];
    s1 += __shfl_xor(s1, 16, 64);  s2 += __shfl_xor(s2, 16, 64);
    s1 += __shfl_xor(s1, 32, 64);  s2 += __shfl_xor(s2, 32, 64);
    if (quad == 0){
      atomicAdd(&stats[bucket*128 + nt*16 + l15], s1);
      atomicAdd(&stats[bucket*128 + 64 + nt*16 + l15], s2);
    }
  }

  const size_t slab_off = (size_t)slab * OUTN_;
  const int h = h0 + wv;
  #pragma unroll
  for (int mh = 0; mh < 2; ++mh)
    #pragma unroll
    for (int nt = 0; nt < 4; ++nt){
      int o = nt*16 + l15;
      #pragma unroll
      for (int rg = 0; rg < 4; ++rg){
        int w = mh*16 + quad*4 + rg;
        size_t idx = slab_off + ((size_t)(b*64 + o))*HW_ + h*W_ + w;
        maxp[idx] = __float2bfloat16(mmx[mh][nt][rg]);
        minp[idx] = __float2bfloat16(mmn[mh][nt][rg]);
      }
    }
}

// ---------------- final: reduce slabs, apply BN3+ReLU via monotonicity ----------------

__global__ void bevreduce_kernel(const bf16* __restrict__ minp, const bf16* __restrict__ maxp,
                                 const float* __restrict__ ss, float* __restrict__ out, int nslab){
  int j = blockIdx.x*blockDim.x + threadIdx.x;
  if (j >= OUTN_) return;
  int o = (j >> 12) & 63;
  float mx = -FLT_MAX, mn = FLT_MAX;
  for (int s = 0; s < nslab; ++s){
    mx = fmaxf(mx, __bfloat162float(maxp[(size_t)s*OUTN_ + j]));
    mn = fminf(mn, __bfloat162float(minp[(size_t)s*OUTN_ + j]));
  }
  float a = ss[o], sh = ss[64 + o];
  float v = (a >= 0.f) ? mx : mn;   // relu(a*z+s) monotone in z, direction sign(a)
  out[j] = fmaxf(fmaf(a, v, sh), 0.f);
}

// ---------------- BN finalize: sum buckets, scale/shift ----------------

__global__ void finalize_kernel(const float* __restrict__ stb, const float* __restrict__ gamma,
                                const float* __restrict__ beta, float* __restrict__ ss, int C){
  int c = threadIdx.x;
  if (c >= C) return;
  float s1 = 0.f, s2 = 0.f;
  for (int k = 0; k < NBUCK; ++k){
    s1 += stb[k*128 + c];
    s2 += stb[k*128 + C + c];
  }
  const float invCnt = 1.0f / (float)((size_t)B_*DHW_);
  float mean = s1 * invCnt;
  float var  = s2 * invCnt - mean*mean;
  float a = gamma[c] * rsqrtf(var + EPSV);
  ss[c]     = a;
  ss[C + c] = beta[c] - mean*a;
}

// ---------------- launch ----------------

extern "C" void kernel_launch(void* const* d_in, const int* in_sizes, int n_in,
                              void* d_out, int out_size, void* d_ws, size_t ws_size,
                              hipStream_t stream){
  const float* pc  = (const float*)d_in[0];
  const float* w1  = (const float*)d_in[1];
  const float* b1  = (const float*)d_in[2];
  const float* g1  = (const float*)d_in[3];
  const float* be1 = (const float*)d_in[4];
  const float* w2  = (const float*)d_in[5];
  const float* b2  = (const float*)d_in[6];
  const float* g2  = (const float*)d_in[7];
  const float* be2 = (const float*)d_in[8];
  const float* w3  = (const float*)d_in[9];
  const float* b3  = (const float*)d_in[10];
  const float* g3  = (const float*)d_in[11];
  const float* be3 = (const float*)d_in[12];
  const int N = in_sizes[0] / 6;  // (B=2, 3, N)
  float* out = (float*)d_out;

  char* wsb = (char*)d_ws;
  size_t off = 0;
  auto alloc = [&](size_t bytes)->char*{
    off = (off + 255) & ~(size_t)255;
    char* p = wsb + off; off += bytes; return p;
  };
  float* g0   = (float*)alloc((size_t)B_*DHW_*4);   // 4 MB
  float* wr1  = (float*)alloc(864*4);               // [27k][32o] fp32
  float* wr2  = (float*)alloc(55296*4);             // fp32 (fallback fused12)
  bf16*  wr2b = (bf16*) alloc(55296*2);             // [tap][64o][32i] bf16
  bf16*  wr3b = (bf16*) alloc(110592*2);            // [tap][64o][64i] bf16
  float* mins = (float*)alloc(8*4);
  float* stb  = (float*)alloc((size_t)3*NBUCK*128*4); // bucketed stats, 192 KB
  float* ss   = (float*)alloc(3*128*4);

  constexpr int DCHUNK = 16;
  constexpr int NSLAB  = D_ / DCHUNK;               // 8
  const size_t SX1  = (size_t)B_*DHW_*32*2;         // 64 MiB channel-last bf16
  const size_t SX2  = (size_t)B_*DHW_*64*2;         // 128 MiB channel-last bf16
  const size_t SMM  = (size_t)NSLAB*OUTN_*2;        // 8 MiB per min/max array

  // regionR: x1 (64MiB) aliases minp/maxp (16MiB) — disjoint lifetimes
  const size_t prefixEnd = (off + 255) & ~(size_t)255;
  const bool useMfma2 = ws_size >= prefixEnd + SX1 + SX2 + 1024;

  char* regionR = alloc(useMfma2 ? SX1 : 2*SMM);
  bf16* maxp = (bf16*)regionR;
  bf16* minp = (bf16*)(regionR + SMM);
  bf16* x1   = (bf16*)regionR;
  bf16* x2   = (bf16*)alloc(SX2);

  float* st1 = stb;
  float* st2 = stb + (size_t)NBUCK*128;
  float* st3 = stb + (size_t)2*NBUCK*128;

  // prologue
  zero_kernel<<<(B_*DHW_ + 255)/256, 256, 0, stream>>>(g0, B_*DHW_);
  zero_kernel<<<(3*NBUCK*128 + 255)/256, 256, 0, stream>>>(stb, 3*NBUCK*128);
  min_kernel<<<B_*3, 256, 0, stream>>>(pc, mins, N);
  scatter_kernel<<<(B_*N + 255)/256, 256, 0, stream>>>(pc, mins, g0, N);
  reorder_kernel<<<(864 + 255)/256, 256, 0, stream>>>(w1, wr1, 1, 32);
  reorder_kernel<<<(55296 + 255)/256, 256, 0, stream>>>(w2, wr2, 32, 64);
  reorder2b_kernel<<<(55296 + 255)/256, 256, 0, stream>>>(w2, wr2b);
  reorder3b_kernel<<<(110592 + 255)/256, 256, 0, stream>>>(w3, wr3b);

  dim3 cgrid(16, 128, 2);                           // (8h-tiles, d, b)
  dim3 mgrid(32, NSLAB, 2);                         // (4h-tiles, d-slabs, b) = 512 blocks

  if (useMfma2){
    conv1act_kernel<<<cgrid, 256, 0, stream>>>(g0, wr1, b1, x1, st1);
    finalize_kernel<<<1, 64, 0, stream>>>(st1, g1, be1, ss, 32);
    conv2mfma_kernel<DCHUNK><<<mgrid, 256, 0, stream>>>(x1, wr2b, ss, b2, x2, st2);
  } else {
    convstats_kernel<<<cgrid, 256, 0, stream>>>(g0, wr1, b1, st1);
    finalize_kernel<<<1, 64, 0, stream>>>(st1, g1, be1, ss, 32);
    fused12_kernel<<<cgrid, 256, 0, stream>>>(g0, wr1, b1, ss, wr2, b2, x2, st2);
  }
  finalize_kernel<<<1, 64, 0, stream>>>(st2, g2, be2, ss + 128, 64);

  conv3mfma_kernel<DCHUNK><<<mgrid, 256, 0, stream>>>(x2, wr3b, ss + 128, b3, st3, minp, maxp);
  finalize_kernel<<<1, 64, 0, stream>>>(st3, g3, be3, ss + 256, 64);
  bevreduce_kernel<<<(OUTN_ + 255)/256, 256, 0, stream>>>(minp, maxp, ss + 256, out, NSLAB);
}

// Round 13
// 857.111 us; speedup vs baseline: 1.7221x; 1.5917x over previous
//
#include <hip/hip_runtime.h>
#include <hip/hip_bf16.h>
#include <float.h>

// LiDAR BEV pipeline (fp32 I/O):
//   voxelize -> conv3d(1->32)+BN+ReLU -> conv3d(32->64)+BN+ReLU -> conv3d(64->64)+BN+ReLU -> max over D
// R12 post-mortem: XCD swizzle moved nothing; the ~1GB excess FETCH is per-wave WEIGHT
// fragment gathers (each wave re-reads the whole weight array per d-pair: conv2 1.77GB,
// conv3 3.5GB logical). R13: weights staged ONCE per block into LDS ([tap][ichunk][o][8],
// conflict-free 16B fragment reads). conv2: 110KB weights + 52KB A-tile = 163KB LDS,
// 1 block/CU. conv3: o-halved blocks (1024) so its weight half fits the same budget.

#define VOXEL 0.0625f
#define D_ 128
#define H_ 128
#define W_ 32
#define HW_ (H_*W_)      // 4096
#define DHW_ (D_*H_*W_)  // 524288
#define B_ 2
#define EPSV 1e-5f
#define OUTN_ (B_*64*HW_) // 524288
#define NBUCK 128         // stats buckets

typedef __hip_bfloat16 bf16;
typedef __attribute__((ext_vector_type(8))) short short8;   // 8 bf16
typedef __attribute__((ext_vector_type(4))) short short4v;  // 4 bf16
typedef __attribute__((ext_vector_type(4))) float f32x4;

__device__ inline void gl_lds16(const void* g, void* l){
  // async global->LDS, 16B per lane; LDS dest = base + lane*16 (wave-uniform base)
  __builtin_amdgcn_global_load_lds(
      (const __attribute__((address_space(1))) unsigned int*)g,
      (__attribute__((address_space(3))) unsigned int*)l, 16, 0, 0);
}

// ---------------- init ----------------

__global__ void zero_kernel(float* __restrict__ p, int n){
  int i = blockIdx.x*blockDim.x + threadIdx.x;
  if (i < n) p[i] = 0.f;
}

// ---------------- voxelize ----------------

__global__ void min_kernel(const float* __restrict__ pc, float* __restrict__ mins, int N){
  const float* base = pc + (size_t)blockIdx.x * N;
  float m = FLT_MAX;
  for (int j = threadIdx.x; j < N; j += blockDim.x){
    float v = base[j];
    if (v != v) v = 0.f;          // NaN -> 0, matching reference
    m = fminf(m, v);
  }
  for (int off = 32; off > 0; off >>= 1)
    m = fminf(m, __shfl_xor(m, off, 64));
  __shared__ float red[4];
  int wave = threadIdx.x >> 6;
  if ((threadIdx.x & 63) == 0) red[wave] = m;
  __syncthreads();
  if (threadIdx.x == 0){
    float r = red[0];
    for (int k = 1; k < (int)(blockDim.x >> 6); ++k) r = fminf(r, red[k]);
    mins[blockIdx.x] = r;
  }
}

__global__ void scatter_kernel(const float* __restrict__ pc, const float* __restrict__ mins,
                               float* __restrict__ grid, int N){
  int idx = blockIdx.x*blockDim.x + threadIdx.x;
  if (idx >= B_*N) return;
  int b = idx / N, n = idx - b*N;
  float x = pc[((size_t)b*3 + 0)*N + n];
  float y = pc[((size_t)b*3 + 1)*N + n];
  float z = pc[((size_t)b*3 + 2)*N + n];
  if (x != x) x = 0.f;
  if (y != y) y = 0.f;
  if (z != z) z = 0.f;
  int ix = (int)floorf((x - mins[b*3+0]) / VOXEL);
  int iy = (int)floorf((y - mins[b*3+1]) / VOXEL);
  int iz = (int)floorf((z - mins[b*3+2]) / VOXEL);
  ix = min(max(ix, 0), D_-1);
  iy = min(max(iy, 0), H_-1);
  iz = min(max(iz, 0), W_-1);
  grid[(size_t)b*DHW_ + (size_t)ix*HW_ + iy*W_ + iz] = 1.0f;
}

// ---------------- weight reorders ----------------

__global__ void reorder_kernel(const float* __restrict__ w, float* __restrict__ wr, int CIN, int COUT){
  int idx = blockIdx.x*blockDim.x + threadIdx.x;
  int total = COUT*CIN*27;
  if (idx >= total) return;
  int o = idx / (CIN*27);
  int rem = idx - o*(CIN*27);
  int i = rem / 27;
  int k = rem - i*27;
  wr[(i*27 + k)*COUT + o] = w[idx];
}

// w2 (64,32,3,3,3) fp32 -> LDS-image layout [tap][i/8][o][i%8] bf16 (55,296 el)
__global__ void reorder2b_kernel(const float* __restrict__ w, bf16* __restrict__ wb){
  int idx = blockIdx.x*blockDim.x + threadIdx.x;
  if (idx >= 64*32*27) return;
  int o = idx / (32*27);
  int rem = idx - o*(32*27);
  int i = rem / 27;
  int tap = rem - i*27;
  wb[(((tap*4 + (i >> 3))*64 + o) << 3) | (i & 7)] = __float2bfloat16(w[idx]);
}

// w3 (64,64,3,3,3) fp32 -> [oh][ic][tap][iq][o'][j] bf16 (two 55,296-el halves)
__global__ void reorder3b_kernel(const float* __restrict__ w, bf16* __restrict__ wb){
  int idx = blockIdx.x*blockDim.x + threadIdx.x;
  if (idx >= 64*64*27) return;
  int o = idx / (64*27);
  int rem = idx - o*(64*27);
  int i = rem / 27;
  int tap = rem - i*27;
  int oh = o >> 5, op = o & 31;
  int ic = i >> 5, iq = (i & 31) >> 3, j = i & 7;
  wb[(((((size_t)(oh*2 + ic)*27 + tap)*4 + iq)*32 + op) << 3) | j] = __float2bfloat16(w[idx]);
}

// ---------------- fp32 conv inner (conv1-class kernels) ----------------

template<int HT, int OPT, int COUT>
__device__ inline void conv_inner(float (*xs)[HT+2][34], float (*wsm)[COUT],
                                  int w, int og, float (*acc)[OPT]){
  #pragma unroll
  for (int kd = 0; kd < 3; ++kd){
    float xr[HT+2][3];
    #pragma unroll
    for (int r = 0; r < HT+2; ++r)
      #pragma unroll
      for (int c = 0; c < 3; ++c)
        xr[r][c] = xs[kd][r][w + c];
    #pragma unroll
    for (int kh = 0; kh < 3; ++kh)
      #pragma unroll
      for (int kw = 0; kw < 3; ++kw){
        const float* wp = &wsm[kd*9 + kh*3 + kw][og*OPT];
        float wv[OPT];
        #pragma unroll
        for (int oo = 0; oo < OPT; ++oo) wv[oo] = wp[oo];
        #pragma unroll
        for (int h = 0; h < HT; ++h){
          float xv = xr[h + kh][kw];
          #pragma unroll
          for (int oo = 0; oo < OPT; ++oo)
            acc[h][oo] = fmaf(xv, wv[oo], acc[h][oo]);
        }
      }
  }
}

// ---------------- conv1 BN stats only (fallback path) ----------------

__global__ __launch_bounds__(256)
void convstats_kernel(const float* __restrict__ X, const float* __restrict__ WR,
                      const float* __restrict__ bias, float* __restrict__ stats){
  const int tid = threadIdx.x;
  const int w   = tid & 31;
  const int og  = tid >> 5;
  const int h0  = blockIdx.x * 8;
  const int d   = blockIdx.y;
  const int b   = blockIdx.z;
  const int bucket = d & (NBUCK - 1);

  __shared__ float xs[3][10][34];
  __shared__ float wsm[27][32];

  float acc[8][4];
  #pragma unroll
  for (int h = 0; h < 8; ++h)
    #pragma unroll
    for (int oo = 0; oo < 4; ++oo) acc[h][oo] = 0.f;

  for (int e = tid; e < 27*32; e += 256)
    ((float*)wsm)[e] = WR[e];
  for (int e = tid; e < 960; e += 256){
    int ds = e / 320; int rem = e - ds*320; int r = rem >> 5; int ww = rem & 31;
    int dd = d + ds - 1, hh = h0 + r - 1;
    float v = 0.f;
    if (dd >= 0 && dd < D_ && hh >= 0 && hh < H_)
      v = X[((size_t)b*D_ + dd)*HW_ + hh*W_ + ww];
    xs[ds][r][ww + 1] = v;
  }
  if (tid < 30){ int ds = tid/10, r = tid - ds*10; xs[ds][r][0] = 0.f; xs[ds][r][33] = 0.f; }
  __syncthreads();
  conv_inner<8, 4, 32>(xs, wsm, w, og, acc);

  #pragma unroll
  for (int oo = 0; oo < 4; ++oo){
    int o = og*4 + oo;
    float bo = bias[o];
    float s1 = 0.f, s2 = 0.f;
    #pragma unroll
    for (int h = 0; h < 8; ++h){
      float y = acc[h][oo] + bo;
      s1 += y;
      s2 = fmaf(y, y, s2);
    }
    for (int m = 16; m > 0; m >>= 1){
      s1 += __shfl_xor(s1, m, 32);
      s2 += __shfl_xor(s2, m, 32);
    }
    if (w == 0){
      atomicAdd(&stats[bucket*128 + o], s1);
      atomicAdd(&stats[bucket*128 + 32 + o], s2);
    }
  }
}

// ---------------- conv1 -> RAW x1 channel-last bf16 [b][d][h][w][32] + BN1 stats ----------------

__global__ __launch_bounds__(256)
void conv1act_kernel(const float* __restrict__ X, const float* __restrict__ WR,
                     const float* __restrict__ bias, bf16* __restrict__ X1,
                     float* __restrict__ stats){
  const int tid = threadIdx.x;
  const int w   = tid & 31;
  const int og  = tid >> 5;
  const int h0  = blockIdx.x * 8;
  const int d   = blockIdx.y;
  const int b   = blockIdx.z;
  const int bucket = d & (NBUCK - 1);

  __shared__ float xs[3][10][34];
  __shared__ float wsm[27][32];

  float acc[8][4];
  #pragma unroll
  for (int h = 0; h < 8; ++h)
    #pragma unroll
    for (int oo = 0; oo < 4; ++oo) acc[h][oo] = 0.f;

  for (int e = tid; e < 27*32; e += 256)
    ((float*)wsm)[e] = WR[e];
  for (int e = tid; e < 960; e += 256){
    int ds = e / 320; int rem = e - ds*320; int r = rem >> 5; int ww = rem & 31;
    int dd = d + ds - 1, hh = h0 + r - 1;
    float v = 0.f;
    if (dd >= 0 && dd < D_ && hh >= 0 && hh < H_)
      v = X[((size_t)b*D_ + dd)*HW_ + hh*W_ + ww];
    xs[ds][r][ww + 1] = v;
  }
  if (tid < 30){ int ds = tid/10, r = tid - ds*10; xs[ds][r][0] = 0.f; xs[ds][r][33] = 0.f; }
  __syncthreads();
  conv_inner<8, 4, 32>(xs, wsm, w, og, acc);

  float bo[4], psum[4], psq[4];
  #pragma unroll
  for (int oo = 0; oo < 4; ++oo){
    bo[oo] = bias[og*4 + oo]; psum[oo] = 0.f; psq[oo] = 0.f;
  }
  #pragma unroll
  for (int h = 0; h < 8; ++h){
    bf16 row[4];
    #pragma unroll
    for (int oo = 0; oo < 4; ++oo){
      float y = acc[h][oo] + bo[oo];
      row[oo] = __float2bfloat16(y);
      psum[oo] += y;
      psq[oo]  = fmaf(y, y, psq[oo]);
    }
    *(short4v*)&X1[((((size_t)b*D_ + d)*H_ + (h0 + h))*W_ + w)*32 + og*4] = *(short4v*)row;
  }
  #pragma unroll
  for (int oo = 0; oo < 4; ++oo){
    float s1 = psum[oo], s2 = psq[oo];
    for (int m = 16; m > 0; m >>= 1){
      s1 += __shfl_xor(s1, m, 32);
      s2 += __shfl_xor(s2, m, 32);
    }
    if (w == 0){
      int o = og*4 + oo;
      atomicAdd(&stats[bucket*128 + o], s1);
      atomicAdd(&stats[bucket*128 + 32 + o], s2);
    }
  }
}

// ---------------- fused12 (fp32 fallback path, writes raw x2 + BN2 stats) ----------------

__global__ __launch_bounds__(256)
void fused12_kernel(const float* __restrict__ G0, const float* __restrict__ WR1,
                    const float* __restrict__ B1, const float* __restrict__ SS1,
                    const float* __restrict__ WR2, const float* __restrict__ B2,
                    bf16* __restrict__ X2, float* __restrict__ stats){
  const int tid = threadIdx.x;
  const int w   = tid & 31;
  const int og  = tid >> 5;
  const int h0  = blockIdx.x * 8;
  const int d   = blockIdx.y;
  const int b   = blockIdx.z;
  const int bucket = d & (NBUCK - 1);

  __shared__ float gs[5][12][34];
  __shared__ float w1s[32][27];
  __shared__ float xs[3][10][34];
  __shared__ float wsm[27][64];

  for (int e = tid; e < 5*12*34; e += 256){
    int ds = e / 408; int rem = e - ds*408; int r = rem / 34; int c = rem - r*34;
    int dd = d - 2 + ds, hh = h0 - 2 + r, ww = c - 1;
    float v = 0.f;
    if (c >= 1 && c <= 32 && dd >= 0 && dd < D_ && hh >= 0 && hh < H_)
      v = G0[((size_t)b*D_ + dd)*HW_ + hh*W_ + ww];
    gs[ds][r][c] = v;
  }
  for (int e = tid; e < 864; e += 256){
    int i = e/27, k = e - 27*i;
    w1s[i][k] = WR1[k*32 + i];
  }

  float acc[8][8];
  #pragma unroll
  for (int h = 0; h < 8; ++h)
    #pragma unroll
    for (int oo = 0; oo < 8; ++oo) acc[h][oo] = 0.f;

  for (int i = 0; i < 32; ++i){
    __syncthreads();
    float a1 = SS1[i];
    float f1 = fmaf(a1, B1[i], SS1[32 + i]);
    for (int e = tid; e < 1020; e += 256){
      int ds = e / 340; int rem = e - ds*340; int r = rem / 34; int c = rem - r*34;
      float v = 0.f;
      int dd = d - 1 + ds, hh = h0 - 1 + r;
      if (c >= 1 && c <= 32 && dd >= 0 && dd < D_ && hh >= 0 && hh < H_){
        float s = 0.f;
        #pragma unroll
        for (int kd = 0; kd < 3; ++kd)
          #pragma unroll
          for (int kh = 0; kh < 3; ++kh)
            #pragma unroll
            for (int kw = 0; kw < 3; ++kw)
              s = fmaf(gs[ds+kd][r+kh][c-1+kw], w1s[i][kd*9+kh*3+kw], s);
        v = fmaxf(fmaf(a1, s, f1), 0.f);
      }
      xs[ds][r][c] = v;
    }
    for (int e = tid; e < 27*64; e += 256)
      ((float*)wsm)[e] = WR2[i*27*64 + e];
    __syncthreads();
    conv_inner<8, 8, 64>(xs, wsm, w, og, acc);
  }

  float bo[8], psum[8], psq[8];
  #pragma unroll
  for (int oo = 0; oo < 8; ++oo){ bo[oo] = B2[og*8 + oo]; psum[oo] = 0.f; psq[oo] = 0.f; }
  #pragma unroll
  for (int h = 0; h < 8; ++h){
    bf16 row[8];
    #pragma unroll
    for (int oo = 0; oo < 8; ++oo){
      float y = acc[h][oo] + bo[oo];
      row[oo] = __float2bfloat16(y);
      psum[oo] += y;
      psq[oo]  = fmaf(y, y, psq[oo]);
    }
    *(short8*)&X2[((((size_t)b*D_ + d)*H_ + (h0 + h))*W_ + w)*64 + og*8] = *(short8*)row;
  }
  #pragma unroll
  for (int oo = 0; oo < 8; ++oo){
    float s1 = psum[oo], s2 = psq[oo];
    for (int m = 16; m > 0; m >>= 1){
      s1 += __shfl_xor(s1, m, 32);
      s2 += __shfl_xor(s2, m, 32);
    }
    if (w == 0){
      atomicAdd(&stats[bucket*128 + og*8 + oo], s1);
      atomicAdd(&stats[bucket*128 + 64 + og*8 + oo], s2);
    }
  }
}

// ---------------- in-LDS BN+ReLU of a staged tile (padding cells stay 0) ----------------
// tile at[4][6][34][32], staged channels = chbase..chbase+31; SS indexed by global channel.

template<int C>
__device__ inline void tile_bnact(bf16 (*at)[6][34][32], const float* __restrict__ SS,
                                  int chbase, int d, int h0, int tid){
  for (int e = tid; e < 4*6*32*4; e += 256){
    int c8 = e & 3;
    int w  = (e >> 2) & 31;
    int r  = (e >> 7) % 6;
    int sl = (e >> 7) / 6;
    int dd = d - 1 + sl, hh = h0 - 1 + r;
    if (dd < 0 || dd >= D_ || hh < 0 || hh >= H_) continue;   // OOB rows stay zero
    bf16* p = &at[sl][r][w + 1][c8*8];
    short8 v = *(short8*)p;
    bf16* pv = (bf16*)&v;
    #pragma unroll
    for (int t = 0; t < 8; ++t){
      int ch = chbase + c8*8 + t;
      pv[t] = __float2bfloat16(fmaxf(fmaf(SS[ch], __bfloat162float(pv[t]), SS[C + ch]), 0.f));
    }
    *(short8*)p = v;
  }
}

// ---------------- conv2 MFMA: weights=A (M=64 o, LDS-resident), activations=B (N=32 w) ----------------
// Weights (110,592B) staged ONCE per block via linear global_load_lds; fragment reads are
// conflict-free ds_read_b128. 1 block/CU (163KB LDS). Reads RAW x1 (BN1+ReLU in-LDS).

template<int DCHUNK>
__global__ __launch_bounds__(256, 1)
void conv2mfma_kernel(const bf16* __restrict__ X1, const bf16* __restrict__ WB,
                      const float* __restrict__ SS1, const float* __restrict__ B2,
                      bf16* __restrict__ X2, float* __restrict__ stats){
  const int tid  = threadIdx.x;
  const int lane = tid & 63;
  const int wv   = tid >> 6;        // wave id = h-row
  const int l15  = lane & 15;
  const int quad = lane >> 4;
  const int h0   = blockIdx.x * 4;
  const int d0   = blockIdx.y * DCHUNK;
  const int b    = blockIdx.z;
  const int bucket = ((int)blockIdx.x | ((int)blockIdx.y << 5)) & (NBUCK - 1);

  __shared__ __align__(16) bf16 at[4][6][34][32];     // 52,224 B
  __shared__ __align__(16) bf16 wsm[27][4][64][8];    // 110,592 B

  // stage ALL weights once (108 x 1KB wave-chunks; linear copy, layout matches global)
  {
    bf16* wl = &wsm[0][0][0][0];
    for (int c = wv; c < 108; c += 4)
      gl_lds16(WB + (size_t)c*512 + lane*8, wl + (size_t)c*512);
  }
  for (int e = tid; e < 4*6*2*32; e += 256){
    int ch = e & 31; int side = (e >> 5) & 1; int r = (e >> 6) % 6; int sl = (e >> 6) / 6;
    at[sl][r][side ? 33 : 0][ch] = __float2bfloat16(0.f);
  }

  f32x4 acc[2][4][2];               // [dp][mt][nt]
  float br[4][4], psum[4][4], psq[4][4];
  #pragma unroll
  for (int mt = 0; mt < 4; ++mt)
    #pragma unroll
    for (int rg = 0; rg < 4; ++rg){
      br[mt][rg] = B2[mt*16 + quad*4 + rg];
      psum[mt][rg] = 0.f; psq[mt][rg] = 0.f;
    }

  const int wlane = lane >> 2;
  const int cq    = lane & 3;

  for (int p = 0; p < DCHUNK/2; ++p){
    const int d = d0 + 2*p;
    #pragma unroll
    for (int dp = 0; dp < 2; ++dp)
      #pragma unroll
      for (int mt = 0; mt < 4; ++mt)
        #pragma unroll
        for (int nt = 0; nt < 2; ++nt)
          acc[dp][mt][nt] = (f32x4){0.f, 0.f, 0.f, 0.f};

    __syncthreads();
    for (int j = wv; j < 24; j += 4){
      int sl = j / 6, r = j - sl*6;
      int dd = d - 1 + sl, hh = h0 - 1 + r;
      if (dd >= 0 && dd < D_ && hh >= 0 && hh < H_){
        const bf16* rowp = X1 + (((size_t)b*D_ + dd)*H_ + hh)*W_*32 + cq*8;
        #pragma unroll
        for (int half = 0; half < 2; ++half)
          gl_lds16(rowp + (size_t)(wlane + half*16)*32, &at[sl][r][1 + half*16][0]);
      } else {
        short8 z = {0,0,0,0,0,0,0,0};
        #pragma unroll
        for (int half = 0; half < 2; ++half)
          *(short8*)(&at[sl][r][1 + half*16][0] + (size_t)lane*8) = z;
      }
    }
    __syncthreads();
    tile_bnact<32>(at, SS1, 0, d, h0, tid);   // BN1+ReLU in LDS
    __syncthreads();

    #pragma unroll
    for (int kd = 0; kd < 3; ++kd)
      #pragma unroll
      for (int kh = 0; kh < 3; ++kh)
        #pragma unroll
        for (int kw = 0; kw < 3; ++kw){
          const int tap = (kd*3 + kh)*3 + kw;
          short8 afw[4];
          #pragma unroll
          for (int mt = 0; mt < 4; ++mt)
            afw[mt] = *(const short8*)&wsm[tap][quad][mt*16 + l15][0];
          #pragma unroll
          for (int dp = 0; dp < 2; ++dp){
            short8 bfa[2];
            #pragma unroll
            for (int nt = 0; nt < 2; ++nt)
              bfa[nt] = *(const short8*)&at[dp + kd][wv + kh][nt*16 + l15 + kw][quad*8];
            #pragma unroll
            for (int mt = 0; mt < 4; ++mt)
              #pragma unroll
              for (int nt = 0; nt < 2; ++nt)
                acc[dp][mt][nt] = __builtin_amdgcn_mfma_f32_16x16x32_bf16(afw[mt], bfa[nt], acc[dp][mt][nt], 0, 0, 0);
          }
        }

    // pair epilogue: bias, stats, 8B stores (4 consecutive o)
    #pragma unroll
    for (int dp = 0; dp < 2; ++dp){
      const size_t rowbase = (((size_t)b*D_ + (d + dp))*H_ + (h0 + wv))*W_;
      #pragma unroll
      for (int nt = 0; nt < 2; ++nt){
        const size_t pix = (rowbase + nt*16 + l15)*64;
        #pragma unroll
        for (int mt = 0; mt < 4; ++mt){
          bf16 row[4];
          #pragma unroll
          for (int rg = 0; rg < 4; ++rg){
            float y = acc[dp][mt][nt][rg] + br[mt][rg];
            psum[mt][rg] += y;
            psq[mt][rg]  = fmaf(y, y, psq[mt][rg]);
            row[rg] = __float2bfloat16(y);
          }
          *(short4v*)&X2[pix + mt*16 + quad*4] = *(short4v*)row;
        }
      }
    }
  }

  // BN2 stats: reduce across l15, bucketed atomics from l15==0
  #pragma unroll
  for (int mt = 0; mt < 4; ++mt)
    #pragma unroll
    for (int rg = 0; rg < 4; ++rg){
      float s1 = psum[mt][rg], s2 = psq[mt][rg];
      #pragma unroll
      for (int m = 1; m < 16; m <<= 1){
        s1 += __shfl_xor(s1, m, 64);
        s2 += __shfl_xor(s2, m, 64);
      }
      if (l15 == 0){
        int o = mt*16 + quad*4 + rg;
        atomicAdd(&stats[bucket*128 + o], s1);
        atomicAdd(&stats[bucket*128 + 64 + o], s2);
      }
    }
}

// ---------------- conv3 MFMA (o-halved): RAW x2 in (BN2+ReLU in-LDS), weights LDS-resident ----------------

template<int DCHUNK>
__global__ __launch_bounds__(256, 1)
void conv3mfma_kernel(const bf16* __restrict__ X, const bf16* __restrict__ WB,
                      const float* __restrict__ SS2, const float* __restrict__ bias,
                      float* __restrict__ stats, bf16* __restrict__ minp, bf16* __restrict__ maxp){
  const int tid  = threadIdx.x;
  const int lane = tid & 63;
  const int wv   = tid >> 6;
  const int l15  = lane & 15;
  const int quad = lane >> 4;
  const int hb   = blockIdx.x & 31;
  const int oh   = blockIdx.x >> 5;       // o half
  const int h0   = hb * 4;
  const int d0   = blockIdx.y * DCHUNK;
  const int b    = blockIdx.z;
  const int bucket = (hb | ((int)blockIdx.y << 5) | (oh << 6)) & (NBUCK - 1);

  __shared__ __align__(16) bf16 at[4][6][34][32];        // 52,224 B
  __shared__ __align__(16) bf16 wsm[2][27][4][32][8];    // 110,592 B (this oh half)

  {
    bf16* wl = &wsm[0][0][0][0][0];
    const bf16* wg = WB + (size_t)oh*55296;
    for (int c = wv; c < 108; c += 4)
      gl_lds16(wg + (size_t)c*512 + lane*8, wl + (size_t)c*512);
  }
  for (int e = tid; e < 4*6*2*32; e += 256){
    int ch = e & 31; int side = (e >> 5) & 1; int r = (e >> 6) % 6; int sl = (e >> 6) / 6;
    at[sl][r][side ? 33 : 0][ch] = __float2bfloat16(0.f);
  }

  f32x4 acc[2][2][2];               // [dp][mh][nt]
  float mmx[2][2][4], mmn[2][2][4]; // [mh][nt][rg]
  float brg[2];
  #pragma unroll
  for (int nt = 0; nt < 2; ++nt) brg[nt] = bias[oh*32 + nt*16 + l15];
  #pragma unroll
  for (int mh = 0; mh < 2; ++mh)
    #pragma unroll
    for (int nt = 0; nt < 2; ++nt)
      #pragma unroll
      for (int rg = 0; rg < 4; ++rg){ mmx[mh][nt][rg] = -FLT_MAX; mmn[mh][nt][rg] = FLT_MAX; }
  float psum[2] = {0.f,0.f}, psq[2] = {0.f,0.f};

  const int wlane = lane >> 2;
  const int cq    = lane & 3;

  for (int p = 0; p < DCHUNK/2; ++p){
    const int d = d0 + 2*p;
    #pragma unroll
    for (int dp = 0; dp < 2; ++dp)
      #pragma unroll
      for (int mh = 0; mh < 2; ++mh)
        #pragma unroll
        for (int nt = 0; nt < 2; ++nt)
          acc[dp][mh][nt] = (f32x4){0.f, 0.f, 0.f, 0.f};

    for (int ic = 0; ic < 2; ++ic){
      __syncthreads();
      for (int j = wv; j < 24; j += 4){
        int sl = j / 6, r = j - sl*6;
        int dd = d - 1 + sl, hh = h0 - 1 + r;
        if (dd >= 0 && dd < D_ && hh >= 0 && hh < H_){
          const bf16* rowp = X + (((size_t)b*D_ + dd)*H_ + hh)*W_*64 + ic*32 + cq*8;
          #pragma unroll
          for (int half = 0; half < 2; ++half)
            gl_lds16(rowp + (size_t)(wlane + half*16)*64, &at[sl][r][1 + half*16][0]);
        } else {
          short8 z = {0,0,0,0,0,0,0,0};
          #pragma unroll
          for (int half = 0; half < 2; ++half)
            *(short8*)(&at[sl][r][1 + half*16][0] + (size_t)lane*8) = z;
        }
      }
      __syncthreads();
      tile_bnact<64>(at, SS2, ic*32, d, h0, tid);   // BN2+ReLU in LDS
      __syncthreads();

      #pragma unroll
      for (int kd = 0; kd < 3; ++kd)
        #pragma unroll
        for (int kh = 0; kh < 3; ++kh)
          #pragma unroll
          for (int kw = 0; kw < 3; ++kw){
            const int tap = (kd*3 + kh)*3 + kw;
            short8 bfr[2];
            #pragma unroll
            for (int nt = 0; nt < 2; ++nt)
              bfr[nt] = *(const short8*)&wsm[ic][tap][quad][nt*16 + l15][0];
            #pragma unroll
            for (int dp = 0; dp < 2; ++dp){
              short8 af[2];
              #pragma unroll
              for (int mh = 0; mh < 2; ++mh)
                af[mh] = *(const short8*)&at[dp + kd][wv + kh][mh*16 + l15 + kw][quad*8];
              #pragma unroll
              for (int mh = 0; mh < 2; ++mh)
                #pragma unroll
                for (int nt = 0; nt < 2; ++nt)
                  acc[dp][mh][nt] = __builtin_amdgcn_mfma_f32_16x16x32_bf16(af[mh], bfr[nt], acc[dp][mh][nt], 0, 0, 0);
            }
          }
    }

    #pragma unroll
    for (int dp = 0; dp < 2; ++dp)
      #pragma unroll
      for (int mh = 0; mh < 2; ++mh)
        #pragma unroll
        for (int nt = 0; nt < 2; ++nt)
          #pragma unroll
          for (int rg = 0; rg < 4; ++rg){
            float y = acc[dp][mh][nt][rg] + brg[nt];
            psum[nt] += y;
            psq[nt]  = fmaf(y, y, psq[nt]);
            mmx[mh][nt][rg] = fmaxf(mmx[mh][nt][rg], y);
            mmn[mh][nt][rg] = fminf(mmn[mh][nt][rg], y);
          }
  }

  // BN3 stats: lanes {l15, +16, +32, +48} share o = oh*32 + nt*16 + l15
  #pragma unroll
  for (int nt = 0; nt < 2; ++nt){
    float s1 = psum[nt], s2 = psq[nt];
    s1 += __shfl_xor(s1, 16, 64);  s2 += __shfl_xor(s2, 16, 64);
    s1 += __shfl_xor(s1, 32, 64);  s2 += __shfl_xor(s2, 32, 64);
    if (quad == 0){
      int o = oh*32 + nt*16 + l15;
      atomicAdd(&stats[bucket*128 + o], s1);
      atomicAdd(&stats[bucket*128 + 64 + o], s2);
    }
  }

  const size_t slab_off = (size_t)blockIdx.y * OUTN_;
  const int h = h0 + wv;
  #pragma unroll
  for (int mh = 0; mh < 2; ++mh)
    #pragma unroll
    for (int nt = 0; nt < 2; ++nt){
      int o = oh*32 + nt*16 + l15;
      #pragma unroll
      for (int rg = 0; rg < 4; ++rg){
        int w = mh*16 + quad*4 + rg;
        size_t idx = slab_off + ((size_t)(b*64 + o))*HW_ + h*W_ + w;
        maxp[idx] = __float2bfloat16(mmx[mh][nt][rg]);
        minp[idx] = __float2bfloat16(mmn[mh][nt][rg]);
      }
    }
}

// ---------------- final: reduce slabs, apply BN3+ReLU via monotonicity ----------------

__global__ void bevreduce_kernel(const bf16* __restrict__ minp, const bf16* __restrict__ maxp,
                                 const float* __restrict__ ss, float* __restrict__ out, int nslab){
  int j = blockIdx.x*blockDim.x + threadIdx.x;
  if (j >= OUTN_) return;
  int o = (j >> 12) & 63;
  float mx = -FLT_MAX, mn = FLT_MAX;
  for (int s = 0; s < nslab; ++s){
    mx = fmaxf(mx, __bfloat162float(maxp[(size_t)s*OUTN_ + j]));
    mn = fminf(mn, __bfloat162float(minp[(size_t)s*OUTN_ + j]));
  }
  float a = ss[o], sh = ss[64 + o];
  float v = (a >= 0.f) ? mx : mn;   // relu(a*z+s) monotone in z, direction sign(a)
  out[j] = fmaxf(fmaf(a, v, sh), 0.f);
}

// ---------------- BN finalize: sum buckets, scale/shift ----------------

__global__ void finalize_kernel(const float* __restrict__ stb, const float* __restrict__ gamma,
                                const float* __restrict__ beta, float* __restrict__ ss, int C){
  int c = threadIdx.x;
  if (c >= C) return;
  float s1 = 0.f, s2 = 0.f;
  for (int k = 0; k < NBUCK; ++k){
    s1 += stb[k*128 + c];
    s2 += stb[k*128 + C + c];
  }
  const float invCnt = 1.0f / (float)((size_t)B_*DHW_);
  float mean = s1 * invCnt;
  float var  = s2 * invCnt - mean*mean;
  float a = gamma[c] * rsqrtf(var + EPSV);
  ss[c]     = a;
  ss[C + c] = beta[c] - mean*a;
}

// ---------------- launch ----------------

extern "C" void kernel_launch(void* const* d_in, const int* in_sizes, int n_in,
                              void* d_out, int out_size, void* d_ws, size_t ws_size,
                              hipStream_t stream){
  const float* pc  = (const float*)d_in[0];
  const float* w1  = (const float*)d_in[1];
  const float* b1  = (const float*)d_in[2];
  const float* g1  = (const float*)d_in[3];
  const float* be1 = (const float*)d_in[4];
  const float* w2  = (const float*)d_in[5];
  const float* b2  = (const float*)d_in[6];
  const float* g2  = (const float*)d_in[7];
  const float* be2 = (const float*)d_in[8];
  const float* w3  = (const float*)d_in[9];
  const float* b3  = (const float*)d_in[10];
  const float* g3  = (const float*)d_in[11];
  const float* be3 = (const float*)d_in[12];
  const int N = in_sizes[0] / 6;  // (B=2, 3, N)
  float* out = (float*)d_out;

  char* wsb = (char*)d_ws;
  size_t off = 0;
  auto alloc = [&](size_t bytes)->char*{
    off = (off + 255) & ~(size_t)255;
    char* p = wsb + off; off += bytes; return p;
  };
  float* g0   = (float*)alloc((size_t)B_*DHW_*4);   // 4 MB
  float* wr1  = (float*)alloc(864*4);               // [27k][32o] fp32
  float* wr2  = (float*)alloc(55296*4);             // fp32 (fallback fused12)
  bf16*  wr2b = (bf16*) alloc(55296*2);             // conv2 LDS-image layout
  bf16*  wr3b = (bf16*) alloc(110592*2);            // conv3 [oh][ic][tap][iq][o'][j]
  float* mins = (float*)alloc(8*4);
  float* stb  = (float*)alloc((size_t)3*NBUCK*128*4); // bucketed stats, 192 KB
  float* ss   = (float*)alloc(3*128*4);

  constexpr int DCHUNK = 16;
  constexpr int NSLAB  = D_ / DCHUNK;               // 8
  const size_t SX1  = (size_t)B_*DHW_*32*2;         // 64 MiB channel-last bf16
  const size_t SX2  = (size_t)B_*DHW_*64*2;         // 128 MiB channel-last bf16
  const size_t SMM  = (size_t)NSLAB*OUTN_*2;        // 8 MiB per min/max array

  // regionR: x1 (64MiB) aliases minp/maxp (16MiB) — disjoint lifetimes
  const size_t prefixEnd = (off + 255) & ~(size_t)255;
  const bool useMfma2 = ws_size >= prefixEnd + SX1 + SX2 + 1024;

  char* regionR = alloc(useMfma2 ? SX1 : 2*SMM);
  bf16* maxp = (bf16*)regionR;
  bf16* minp = (bf16*)(regionR + SMM);
  bf16* x1   = (bf16*)regionR;
  bf16* x2   = (bf16*)alloc(SX2);

  float* st1 = stb;
  float* st2 = stb + (size_t)NBUCK*128;
  float* st3 = stb + (size_t)2*NBUCK*128;

  // prologue
  zero_kernel<<<(B_*DHW_ + 255)/256, 256, 0, stream>>>(g0, B_*DHW_);
  zero_kernel<<<(3*NBUCK*128 + 255)/256, 256, 0, stream>>>(stb, 3*NBUCK*128);
  min_kernel<<<B_*3, 256, 0, stream>>>(pc, mins, N);
  scatter_kernel<<<(B_*N + 255)/256, 256, 0, stream>>>(pc, mins, g0, N);
  reorder_kernel<<<(864 + 255)/256, 256, 0, stream>>>(w1, wr1, 1, 32);
  reorder_kernel<<<(55296 + 255)/256, 256, 0, stream>>>(w2, wr2, 32, 64);
  reorder2b_kernel<<<(55296 + 255)/256, 256, 0, stream>>>(w2, wr2b);
  reorder3b_kernel<<<(110592 + 255)/256, 256, 0, stream>>>(w3, wr3b);

  dim3 cgrid(16, 128, 2);                           // (8h-tiles, d, b)
  dim3 m2grid(32, NSLAB, 2);                        // conv2: 512 blocks
  dim3 m3grid(64, NSLAB, 2);                        // conv3: 1024 blocks (x = hb | oh<<5)

  if (useMfma2){
    conv1act_kernel<<<cgrid, 256, 0, stream>>>(g0, wr1, b1, x1, st1);
    finalize_kernel<<<1, 64, 0, stream>>>(st1, g1, be1, ss, 32);
    conv2mfma_kernel<DCHUNK><<<m2grid, 256, 0, stream>>>(x1, wr2b, ss, b2, x2, st2);
  } else {
    convstats_kernel<<<cgrid, 256, 0, stream>>>(g0, wr1, b1, st1);
    finalize_kernel<<<1, 64, 0, stream>>>(st1, g1, be1, ss, 32);
    fused12_kernel<<<cgrid, 256, 0, stream>>>(g0, wr1, b1, ss, wr2, b2, x2, st2);
  }
  finalize_kernel<<<1, 64, 0, stream>>>(st2, g2, be2, ss + 128, 64);

  conv3mfma_kernel<DCHUNK><<<m3grid, 256, 0, stream>>>(x2, wr3b, ss + 128, b3, st3, minp, maxp);
  finalize_kernel<<<1, 64, 0, stream>>>(st3, g3, be3, ss + 256, 64);
  bevreduce_kernel<<<(OUTN_ + 255)/256, 256, 0, stream>>>(minp, maxp, ss + 256, out, NSLAB);
}

// Round 14
// 639.180 us; speedup vs baseline: 2.3093x; 1.3410x over previous
//
#include <hip/hip_runtime.h>
#include <hip/hip_bf16.h>
#include <float.h>

// LiDAR BEV pipeline (fp32 I/O):
//   voxelize -> conv3d(1->32)+BN+ReLU -> conv3d(32->64)+BN+ReLU -> conv3d(64->64)+BN+ReLU -> max over D
// R13: 857us; conv3mfma 464us at 1 wave/SIMD (163KB LDS -> 1 block/CU), 8-way LDS
// conflicts on A-fragment reads, in-LDS bnact on the critical path. R14:
//  (1) 512-thread blocks, waves split by d-parity sharing the same tile -> 2 waves/SIMD;
//  (2) bnact back to standalone kernels (BW-bound, off critical path);
//  (3) XOR chunk swizzle on the A-tile (pos = chunk ^ ((w'>>1)&3)) -> 2-way (free).

#define VOXEL 0.0625f
#define D_ 128
#define H_ 128
#define W_ 32
#define HW_ (H_*W_)      // 4096
#define DHW_ (D_*H_*W_)  // 524288
#define B_ 2
#define EPSV 1e-5f
#define OUTN_ (B_*64*HW_) // 524288
#define NBUCK 128         // stats buckets

typedef __hip_bfloat16 bf16;
typedef __attribute__((ext_vector_type(8))) short short8;   // 8 bf16
typedef __attribute__((ext_vector_type(4))) short short4v;  // 4 bf16
typedef __attribute__((ext_vector_type(4))) float f32x4;

__device__ inline void gl_lds16(const void* g, void* l){
  // async global->LDS, 16B per lane; LDS dest = base + lane*16 (wave-uniform base)
  __builtin_amdgcn_global_load_lds(
      (const __attribute__((address_space(1))) unsigned int*)g,
      (__attribute__((address_space(3))) unsigned int*)l, 16, 0, 0);
}

// ---------------- init ----------------

__global__ void zero_kernel(float* __restrict__ p, int n){
  int i = blockIdx.x*blockDim.x + threadIdx.x;
  if (i < n) p[i] = 0.f;
}

// ---------------- voxelize ----------------

__global__ void min_kernel(const float* __restrict__ pc, float* __restrict__ mins, int N){
  const float* base = pc + (size_t)blockIdx.x * N;
  float m = FLT_MAX;
  for (int j = threadIdx.x; j < N; j += blockDim.x){
    float v = base[j];
    if (v != v) v = 0.f;          // NaN -> 0, matching reference
    m = fminf(m, v);
  }
  for (int off = 32; off > 0; off >>= 1)
    m = fminf(m, __shfl_xor(m, off, 64));
  __shared__ float red[4];
  int wave = threadIdx.x >> 6;
  if ((threadIdx.x & 63) == 0) red[wave] = m;
  __syncthreads();
  if (threadIdx.x == 0){
    float r = red[0];
    for (int k = 1; k < (int)(blockDim.x >> 6); ++k) r = fminf(r, red[k]);
    mins[blockIdx.x] = r;
  }
}

__global__ void scatter_kernel(const float* __restrict__ pc, const float* __restrict__ mins,
                               float* __restrict__ grid, int N){
  int idx = blockIdx.x*blockDim.x + threadIdx.x;
  if (idx >= B_*N) return;
  int b = idx / N, n = idx - b*N;
  float x = pc[((size_t)b*3 + 0)*N + n];
  float y = pc[((size_t)b*3 + 1)*N + n];
  float z = pc[((size_t)b*3 + 2)*N + n];
  if (x != x) x = 0.f;
  if (y != y) y = 0.f;
  if (z != z) z = 0.f;
  int ix = (int)floorf((x - mins[b*3+0]) / VOXEL);
  int iy = (int)floorf((y - mins[b*3+1]) / VOXEL);
  int iz = (int)floorf((z - mins[b*3+2]) / VOXEL);
  ix = min(max(ix, 0), D_-1);
  iy = min(max(iy, 0), H_-1);
  iz = min(max(iz, 0), W_-1);
  grid[(size_t)b*DHW_ + (size_t)ix*HW_ + iy*W_ + iz] = 1.0f;
}

// ---------------- weight reorders ----------------

__global__ void reorder_kernel(const float* __restrict__ w, float* __restrict__ wr, int CIN, int COUT){
  int idx = blockIdx.x*blockDim.x + threadIdx.x;
  int total = COUT*CIN*27;
  if (idx >= total) return;
  int o = idx / (CIN*27);
  int rem = idx - o*(CIN*27);
  int i = rem / 27;
  int k = rem - i*27;
  wr[(i*27 + k)*COUT + o] = w[idx];
}

// w2 (64,32,3,3,3) fp32 -> LDS-image layout [tap][i/8][o][i%8] bf16 (55,296 el)
__global__ void reorder2b_kernel(const float* __restrict__ w, bf16* __restrict__ wb){
  int idx = blockIdx.x*blockDim.x + threadIdx.x;
  if (idx >= 64*32*27) return;
  int o = idx / (32*27);
  int rem = idx - o*(32*27);
  int i = rem / 27;
  int tap = rem - i*27;
  wb[(((tap*4 + (i >> 3))*64 + o) << 3) | (i & 7)] = __float2bfloat16(w[idx]);
}

// w3 (64,64,3,3,3) fp32 -> [oh][ic][tap][iq][o'][j] bf16 (two 55,296-el halves)
__global__ void reorder3b_kernel(const float* __restrict__ w, bf16* __restrict__ wb){
  int idx = blockIdx.x*blockDim.x + threadIdx.x;
  if (idx >= 64*64*27) return;
  int o = idx / (64*27);
  int rem = idx - o*(64*27);
  int i = rem / 27;
  int tap = rem - i*27;
  int oh = o >> 5, op = o & 31;
  int ic = i >> 5, iq = (i & 31) >> 3, j = i & 7;
  wb[(((((size_t)(oh*2 + ic)*27 + tap)*4 + iq)*32 + op) << 3) | j] = __float2bfloat16(w[idx]);
}

// ---------------- fp32 conv inner (conv1-class kernels) ----------------

template<int HT, int OPT, int COUT>
__device__ inline void conv_inner(float (*xs)[HT+2][34], float (*wsm)[COUT],
                                  int w, int og, float (*acc)[OPT]){
  #pragma unroll
  for (int kd = 0; kd < 3; ++kd){
    float xr[HT+2][3];
    #pragma unroll
    for (int r = 0; r < HT+2; ++r)
      #pragma unroll
      for (int c = 0; c < 3; ++c)
        xr[r][c] = xs[kd][r][w + c];
    #pragma unroll
    for (int kh = 0; kh < 3; ++kh)
      #pragma unroll
      for (int kw = 0; kw < 3; ++kw){
        const float* wp = &wsm[kd*9 + kh*3 + kw][og*OPT];
        float wv[OPT];
        #pragma unroll
        for (int oo = 0; oo < OPT; ++oo) wv[oo] = wp[oo];
        #pragma unroll
        for (int h = 0; h < HT; ++h){
          float xv = xr[h + kh][kw];
          #pragma unroll
          for (int oo = 0; oo < OPT; ++oo)
            acc[h][oo] = fmaf(xv, wv[oo], acc[h][oo]);
        }
      }
  }
}

// ---------------- conv1 BN stats only (fallback path) ----------------

__global__ __launch_bounds__(256)
void convstats_kernel(const float* __restrict__ X, const float* __restrict__ WR,
                      const float* __restrict__ bias, float* __restrict__ stats){
  const int tid = threadIdx.x;
  const int w   = tid & 31;
  const int og  = tid >> 5;
  const int h0  = blockIdx.x * 8;
  const int d   = blockIdx.y;
  const int b   = blockIdx.z;
  const int bucket = d & (NBUCK - 1);

  __shared__ float xs[3][10][34];
  __shared__ float wsm[27][32];

  float acc[8][4];
  #pragma unroll
  for (int h = 0; h < 8; ++h)
    #pragma unroll
    for (int oo = 0; oo < 4; ++oo) acc[h][oo] = 0.f;

  for (int e = tid; e < 27*32; e += 256)
    ((float*)wsm)[e] = WR[e];
  for (int e = tid; e < 960; e += 256){
    int ds = e / 320; int rem = e - ds*320; int r = rem >> 5; int ww = rem & 31;
    int dd = d + ds - 1, hh = h0 + r - 1;
    float v = 0.f;
    if (dd >= 0 && dd < D_ && hh >= 0 && hh < H_)
      v = X[((size_t)b*D_ + dd)*HW_ + hh*W_ + ww];
    xs[ds][r][ww + 1] = v;
  }
  if (tid < 30){ int ds = tid/10, r = tid - ds*10; xs[ds][r][0] = 0.f; xs[ds][r][33] = 0.f; }
  __syncthreads();
  conv_inner<8, 4, 32>(xs, wsm, w, og, acc);

  #pragma unroll
  for (int oo = 0; oo < 4; ++oo){
    int o = og*4 + oo;
    float bo = bias[o];
    float s1 = 0.f, s2 = 0.f;
    #pragma unroll
    for (int h = 0; h < 8; ++h){
      float y = acc[h][oo] + bo;
      s1 += y;
      s2 = fmaf(y, y, s2);
    }
    for (int m = 16; m > 0; m >>= 1){
      s1 += __shfl_xor(s1, m, 32);
      s2 += __shfl_xor(s2, m, 32);
    }
    if (w == 0){
      atomicAdd(&stats[bucket*128 + o], s1);
      atomicAdd(&stats[bucket*128 + 32 + o], s2);
    }
  }
}

// ---------------- conv1 -> RAW x1 channel-last bf16 [b][d][h][w][32] + BN1 stats ----------------

__global__ __launch_bounds__(256)
void conv1act_kernel(const float* __restrict__ X, const float* __restrict__ WR,
                     const float* __restrict__ bias, bf16* __restrict__ X1,
                     float* __restrict__ stats){
  const int tid = threadIdx.x;
  const int w   = tid & 31;
  const int og  = tid >> 5;
  const int h0  = blockIdx.x * 8;
  const int d   = blockIdx.y;
  const int b   = blockIdx.z;
  const int bucket = d & (NBUCK - 1);

  __shared__ float xs[3][10][34];
  __shared__ float wsm[27][32];

  float acc[8][4];
  #pragma unroll
  for (int h = 0; h < 8; ++h)
    #pragma unroll
    for (int oo = 0; oo < 4; ++oo) acc[h][oo] = 0.f;

  for (int e = tid; e < 27*32; e += 256)
    ((float*)wsm)[e] = WR[e];
  for (int e = tid; e < 960; e += 256){
    int ds = e / 320; int rem = e - ds*320; int r = rem >> 5; int ww = rem & 31;
    int dd = d + ds - 1, hh = h0 + r - 1;
    float v = 0.f;
    if (dd >= 0 && dd < D_ && hh >= 0 && hh < H_)
      v = X[((size_t)b*D_ + dd)*HW_ + hh*W_ + ww];
    xs[ds][r][ww + 1] = v;
  }
  if (tid < 30){ int ds = tid/10, r = tid - ds*10; xs[ds][r][0] = 0.f; xs[ds][r][33] = 0.f; }
  __syncthreads();
  conv_inner<8, 4, 32>(xs, wsm, w, og, acc);

  float bo[4], psum[4], psq[4];
  #pragma unroll
  for (int oo = 0; oo < 4; ++oo){
    bo[oo] = bias[og*4 + oo]; psum[oo] = 0.f; psq[oo] = 0.f;
  }
  #pragma unroll
  for (int h = 0; h < 8; ++h){
    bf16 row[4];
    #pragma unroll
    for (int oo = 0; oo < 4; ++oo){
      float y = acc[h][oo] + bo[oo];
      row[oo] = __float2bfloat16(y);
      psum[oo] += y;
      psq[oo]  = fmaf(y, y, psq[oo]);
    }
    *(short4v*)&X1[((((size_t)b*D_ + d)*H_ + (h0 + h))*W_ + w)*32 + og*4] = *(short4v*)row;
  }
  #pragma unroll
  for (int oo = 0; oo < 4; ++oo){
    float s1 = psum[oo], s2 = psq[oo];
    for (int m = 16; m > 0; m >>= 1){
      s1 += __shfl_xor(s1, m, 32);
      s2 += __shfl_xor(s2, m, 32);
    }
    if (w == 0){
      int o = og*4 + oo;
      atomicAdd(&stats[bucket*128 + o], s1);
      atomicAdd(&stats[bucket*128 + 32 + o], s2);
    }
  }
}

// ---------------- fused12 (fp32 fallback path, writes raw x2 + BN2 stats) ----------------

__global__ __launch_bounds__(256)
void fused12_kernel(const float* __restrict__ G0, const float* __restrict__ WR1,
                    const float* __restrict__ B1, const float* __restrict__ SS1,
                    const float* __restrict__ WR2, const float* __restrict__ B2,
                    bf16* __restrict__ X2, float* __restrict__ stats){
  const int tid = threadIdx.x;
  const int w   = tid & 31;
  const int og  = tid >> 5;
  const int h0  = blockIdx.x * 8;
  const int d   = blockIdx.y;
  const int b   = blockIdx.z;
  const int bucket = d & (NBUCK - 1);

  __shared__ float gs[5][12][34];
  __shared__ float w1s[32][27];
  __shared__ float xs[3][10][34];
  __shared__ float wsm[27][64];

  for (int e = tid; e < 5*12*34; e += 256){
    int ds = e / 408; int rem = e - ds*408; int r = rem / 34; int c = rem - r*34;
    int dd = d - 2 + ds, hh = h0 - 2 + r, ww = c - 1;
    float v = 0.f;
    if (c >= 1 && c <= 32 && dd >= 0 && dd < D_ && hh >= 0 && hh < H_)
      v = G0[((size_t)b*D_ + dd)*HW_ + hh*W_ + ww];
    gs[ds][r][c] = v;
  }
  for (int e = tid; e < 864; e += 256){
    int i = e/27, k = e - 27*i;
    w1s[i][k] = WR1[k*32 + i];
  }

  float acc[8][8];
  #pragma unroll
  for (int h = 0; h < 8; ++h)
    #pragma unroll
    for (int oo = 0; oo < 8; ++oo) acc[h][oo] = 0.f;

  for (int i = 0; i < 32; ++i){
    __syncthreads();
    float a1 = SS1[i];
    float f1 = fmaf(a1, B1[i], SS1[32 + i]);
    for (int e = tid; e < 1020; e += 256){
      int ds = e / 340; int rem = e - ds*340; int r = rem / 34; int c = rem - r*34;
      float v = 0.f;
      int dd = d - 1 + ds, hh = h0 - 1 + r;
      if (c >= 1 && c <= 32 && dd >= 0 && dd < D_ && hh >= 0 && hh < H_){
        float s = 0.f;
        #pragma unroll
        for (int kd = 0; kd < 3; ++kd)
          #pragma unroll
          for (int kh = 0; kh < 3; ++kh)
            #pragma unroll
            for (int kw = 0; kw < 3; ++kw)
              s = fmaf(gs[ds+kd][r+kh][c-1+kw], w1s[i][kd*9+kh*3+kw], s);
        v = fmaxf(fmaf(a1, s, f1), 0.f);
      }
      xs[ds][r][c] = v;
    }
    for (int e = tid; e < 27*64; e += 256)
      ((float*)wsm)[e] = WR2[i*27*64 + e];
    __syncthreads();
    conv_inner<8, 8, 64>(xs, wsm, w, og, acc);
  }

  float bo[8], psum[8], psq[8];
  #pragma unroll
  for (int oo = 0; oo < 8; ++oo){ bo[oo] = B2[og*8 + oo]; psum[oo] = 0.f; psq[oo] = 0.f; }
  #pragma unroll
  for (int h = 0; h < 8; ++h){
    bf16 row[8];
    #pragma unroll
    for (int oo = 0; oo < 8; ++oo){
      float y = acc[h][oo] + bo[oo];
      row[oo] = __float2bfloat16(y);
      psum[oo] += y;
      psq[oo]  = fmaf(y, y, psq[oo]);
    }
    *(short8*)&X2[((((size_t)b*D_ + d)*H_ + (h0 + h))*W_ + w)*64 + og*8] = *(short8*)row;
  }
  #pragma unroll
  for (int oo = 0; oo < 8; ++oo){
    float s1 = psum[oo], s2 = psq[oo];
    for (int m = 16; m > 0; m >>= 1){
      s1 += __shfl_xor(s1, m, 32);
      s2 += __shfl_xor(s2, m, 32);
    }
    if (w == 0){
      atomicAdd(&stats[bucket*128 + og*8 + oo], s1);
      atomicAdd(&stats[bucket*128 + 64 + og*8 + oo], s2);
    }
  }
}

// ---------------- in-place BN+ReLU on channel-last tensor ----------------

template<int C>
__global__ void bnact_kernel(bf16* __restrict__ x, const float* __restrict__ ss){
  size_t i8 = (size_t)blockIdx.x*blockDim.x + threadIdx.x;
  if (i8 >= (size_t)B_*DHW_*(C/8)) return;
  int ob = ((int)(i8 & (C/8 - 1))) * 8;
  bf16* p = x + i8*8;
  short8 v = *(short8*)p;
  bf16* pv = (bf16*)&v;
  #pragma unroll
  for (int j = 0; j < 8; ++j){
    int o = ob + j;
    float f = fmaxf(fmaf(ss[o], __bfloat162float(pv[j]), ss[C + o]), 0.f);
    pv[j] = __float2bfloat16(f);
  }
  *(short8*)p = v;
}

// ---------------- conv2 MFMA (512 thr): weights=A (LDS), activations=B; dp-split waves ----------------
// Wave wv: h-row = wv&3, d-parity = wv>>2. A-tile chunk-swizzled (pos = chunk ^ ((w'>>1)&3))
// so fragment ds_read_b128 are 2-way (free). Pre-activated x1 in (bnact<32> ran before).

template<int DCHUNK>
__global__ __launch_bounds__(512, 2)
void conv2mfma_kernel(const bf16* __restrict__ X1, const bf16* __restrict__ WB,
                      const float* __restrict__ B2, bf16* __restrict__ X2,
                      float* __restrict__ stats){
  const int tid  = threadIdx.x;
  const int lane = tid & 63;
  const int wv   = tid >> 6;        // 0..7
  const int hrow = wv & 3;
  const int dpw  = wv >> 2;         // d parity
  const int l15  = lane & 15;
  const int quad = lane >> 4;
  const int h0   = blockIdx.x * 4;
  const int d0   = blockIdx.y * DCHUNK;
  const int b    = blockIdx.z;
  const int bucket = ((int)blockIdx.x | ((int)blockIdx.y << 5)) & (NBUCK - 1);

  __shared__ __align__(16) bf16 at[4][6][34][32];     // 52,224 B
  __shared__ __align__(16) bf16 wsm[27][4][64][8];    // 110,592 B

  {
    bf16* wl = &wsm[0][0][0][0];
    for (int c = wv; c < 108; c += 8)
      gl_lds16(WB + (size_t)c*512 + lane*8, wl + (size_t)c*512);
  }
  for (int e = tid; e < 4*6*2*32; e += 512){
    int ch = e & 31; int side = (e >> 5) & 1; int r = (e >> 6) % 6; int sl = (e >> 6) / 6;
    at[sl][r][side ? 33 : 0][ch] = __float2bfloat16(0.f);
  }

  f32x4 acc[4][2];                  // [mt][nt]
  float br[4][4], psum[4][4], psq[4][4];
  #pragma unroll
  for (int mt = 0; mt < 4; ++mt)
    #pragma unroll
    for (int rg = 0; rg < 4; ++rg){
      br[mt][rg] = B2[mt*16 + quad*4 + rg];
      psum[mt][rg] = 0.f; psq[mt][rg] = 0.f;
    }

  const int wlane = lane >> 2;
  const int swz   = (((lane >> 2) + 1) >> 1) & 3;       // widx-swizzle (half-independent)
  const int gch   = (lane & 3) ^ swz;                   // global chunk this lane stages

  for (int p = 0; p < DCHUNK/2; ++p){
    const int d = d0 + 2*p;
    #pragma unroll
    for (int mt = 0; mt < 4; ++mt)
      #pragma unroll
      for (int nt = 0; nt < 2; ++nt)
        acc[mt][nt] = (f32x4){0.f, 0.f, 0.f, 0.f};

    __syncthreads();
    for (int j = wv; j < 24; j += 8){
      int sl = j / 6, r = j - sl*6;
      int dd = d - 1 + sl, hh = h0 - 1 + r;
      if (dd >= 0 && dd < D_ && hh >= 0 && hh < H_){
        const bf16* rowp = X1 + (((size_t)b*D_ + dd)*H_ + hh)*W_*32 + gch*8;
        #pragma unroll
        for (int half = 0; half < 2; ++half)
          gl_lds16(rowp + (size_t)(wlane + half*16)*32, &at[sl][r][1 + half*16][0]);
      } else {
        short8 z = {0,0,0,0,0,0,0,0};
        #pragma unroll
        for (int half = 0; half < 2; ++half)
          *(short8*)(&at[sl][r][1 + half*16][0] + (size_t)lane*8) = z;
      }
    }
    __syncthreads();

    #pragma unroll
    for (int kd = 0; kd < 3; ++kd)
      #pragma unroll
      for (int kh = 0; kh < 3; ++kh)
        #pragma unroll
        for (int kw = 0; kw < 3; ++kw){
          const int tap = (kd*3 + kh)*3 + kw;
          short8 afw[4];
          #pragma unroll
          for (int mt = 0; mt < 4; ++mt)
            afw[mt] = *(const short8*)&wsm[tap][quad][mt*16 + l15][0];
          short8 bfa[2];
          #pragma unroll
          for (int nt = 0; nt < 2; ++nt){
            int W = nt*16 + l15 + kw;
            int pq = (quad ^ ((W >> 1) & 3)) * 8;
            bfa[nt] = *(const short8*)&at[dpw + kd][hrow + kh][W][pq];
          }
          #pragma unroll
          for (int mt = 0; mt < 4; ++mt)
            #pragma unroll
            for (int nt = 0; nt < 2; ++nt)
              acc[mt][nt] = __builtin_amdgcn_mfma_f32_16x16x32_bf16(afw[mt], bfa[nt], acc[mt][nt], 0, 0, 0);
        }

    // epilogue: this wave's d row; bias, stats, 8B stores (4 consecutive o)
    {
      const size_t rowbase = (((size_t)b*D_ + (d + dpw))*H_ + (h0 + hrow))*W_;
      #pragma unroll
      for (int nt = 0; nt < 2; ++nt){
        const size_t pix = (rowbase + nt*16 + l15)*64;
        #pragma unroll
        for (int mt = 0; mt < 4; ++mt){
          bf16 row[4];
          #pragma unroll
          for (int rg = 0; rg < 4; ++rg){
            float y = acc[mt][nt][rg] + br[mt][rg];
            psum[mt][rg] += y;
            psq[mt][rg]  = fmaf(y, y, psq[mt][rg]);
            row[rg] = __float2bfloat16(y);
          }
          *(short4v*)&X2[pix + mt*16 + quad*4] = *(short4v*)row;
        }
      }
    }
  }

  // BN2 stats: reduce across l15, bucketed atomics from l15==0
  #pragma unroll
  for (int mt = 0; mt < 4; ++mt)
    #pragma unroll
    for (int rg = 0; rg < 4; ++rg){
      float s1 = psum[mt][rg], s2 = psq[mt][rg];
      #pragma unroll
      for (int m = 1; m < 16; m <<= 1){
        s1 += __shfl_xor(s1, m, 64);
        s2 += __shfl_xor(s2, m, 64);
      }
      if (l15 == 0){
        int o = mt*16 + quad*4 + rg;
        atomicAdd(&stats[bucket*128 + o], s1);
        atomicAdd(&stats[bucket*128 + 64 + o], s2);
      }
    }
}

// ---------------- conv3 MFMA (512 thr, o-halved): pre-act x2 in; BN3 stats + min/max ----------------
// Wave = (h-row, d-parity); min/max partials go to slab 2*blockIdx.y + dpw (16 slabs).

template<int DCHUNK>
__global__ __launch_bounds__(512, 2)
void conv3mfma_kernel(const bf16* __restrict__ X, const bf16* __restrict__ WB,
                      const float* __restrict__ bias, float* __restrict__ stats,
                      bf16* __restrict__ minp, bf16* __restrict__ maxp){
  const int tid  = threadIdx.x;
  const int lane = tid & 63;
  const int wv   = tid >> 6;
  const int hrow = wv & 3;
  const int dpw  = wv >> 2;
  const int l15  = lane & 15;
  const int quad = lane >> 4;
  const int hb   = blockIdx.x & 31;
  const int oh   = blockIdx.x >> 5;       // o half
  const int h0   = hb * 4;
  const int d0   = blockIdx.y * DCHUNK;
  const int b    = blockIdx.z;
  const int bucket = (hb | ((int)blockIdx.y << 5) | (oh << 6)) & (NBUCK - 1);

  __shared__ __align__(16) bf16 at[4][6][34][32];        // 52,224 B
  __shared__ __align__(16) bf16 wsm[2][27][4][32][8];    // 110,592 B (this oh half)

  {
    bf16* wl = &wsm[0][0][0][0][0];
    const bf16* wg = WB + (size_t)oh*55296;
    for (int c = wv; c < 108; c += 8)
      gl_lds16(wg + (size_t)c*512 + lane*8, wl + (size_t)c*512);
  }
  for (int e = tid; e < 4*6*2*32; e += 512){
    int ch = e & 31; int side = (e >> 5) & 1; int r = (e >> 6) % 6; int sl = (e >> 6) / 6;
    at[sl][r][side ? 33 : 0][ch] = __float2bfloat16(0.f);
  }

  f32x4 acc[2][2];                  // [mh][nt]
  float mmx[2][2][4], mmn[2][2][4]; // [mh][nt][rg]
  float brg[2];
  #pragma unroll
  for (int nt = 0; nt < 2; ++nt) brg[nt] = bias[oh*32 + nt*16 + l15];
  #pragma unroll
  for (int mh = 0; mh < 2; ++mh)
    #pragma unroll
    for (int nt = 0; nt < 2; ++nt)
      #pragma unroll
      for (int rg = 0; rg < 4; ++rg){ mmx[mh][nt][rg] = -FLT_MAX; mmn[mh][nt][rg] = FLT_MAX; }
  float psum[2] = {0.f,0.f}, psq[2] = {0.f,0.f};

  const int wlane = lane >> 2;
  const int swz   = (((lane >> 2) + 1) >> 1) & 3;
  const int gch   = (lane & 3) ^ swz;

  for (int p = 0; p < DCHUNK/2; ++p){
    const int d = d0 + 2*p;
    #pragma unroll
    for (int mh = 0; mh < 2; ++mh)
      #pragma unroll
      for (int nt = 0; nt < 2; ++nt)
        acc[mh][nt] = (f32x4){0.f, 0.f, 0.f, 0.f};

    for (int ic = 0; ic < 2; ++ic){
      __syncthreads();
      for (int j = wv; j < 24; j += 8){
        int sl = j / 6, r = j - sl*6;
        int dd = d - 1 + sl, hh = h0 - 1 + r;
        if (dd >= 0 && dd < D_ && hh >= 0 && hh < H_){
          const bf16* rowp = X + (((size_t)b*D_ + dd)*H_ + hh)*W_*64 + ic*32 + gch*8;
          #pragma unroll
          for (int half = 0; half < 2; ++half)
            gl_lds16(rowp + (size_t)(wlane + half*16)*64, &at[sl][r][1 + half*16][0]);
        } else {
          short8 z = {0,0,0,0,0,0,0,0};
          #pragma unroll
          for (int half = 0; half < 2; ++half)
            *(short8*)(&at[sl][r][1 + half*16][0] + (size_t)lane*8) = z;
        }
      }
      __syncthreads();

      #pragma unroll
      for (int kd = 0; kd < 3; ++kd)
        #pragma unroll
        for (int kh = 0; kh < 3; ++kh)
          #pragma unroll
          for (int kw = 0; kw < 3; ++kw){
            const int tap = (kd*3 + kh)*3 + kw;
            short8 bfr[2];
            #pragma unroll
            for (int nt = 0; nt < 2; ++nt)
              bfr[nt] = *(const short8*)&wsm[ic][tap][quad][nt*16 + l15][0];
            short8 af[2];
            #pragma unroll
            for (int mh = 0; mh < 2; ++mh){
              int W = mh*16 + l15 + kw;
              int pq = (quad ^ ((W >> 1) & 3)) * 8;
              af[mh] = *(const short8*)&at[dpw + kd][hrow + kh][W][pq];
            }
            #pragma unroll
            for (int mh = 0; mh < 2; ++mh)
              #pragma unroll
              for (int nt = 0; nt < 2; ++nt)
                acc[mh][nt] = __builtin_amdgcn_mfma_f32_16x16x32_bf16(af[mh], bfr[nt], acc[mh][nt], 0, 0, 0);
          }
    }

    #pragma unroll
    for (int mh = 0; mh < 2; ++mh)
      #pragma unroll
      for (int nt = 0; nt < 2; ++nt)
        #pragma unroll
        for (int rg = 0; rg < 4; ++rg){
          float y = acc[mh][nt][rg] + brg[nt];
          psum[nt] += y;
          psq[nt]  = fmaf(y, y, psq[nt]);
          mmx[mh][nt][rg] = fmaxf(mmx[mh][nt][rg], y);
          mmn[mh][nt][rg] = fminf(mmn[mh][nt][rg], y);
        }
  }

  // BN3 stats: lanes {l15, +16, +32, +48} share o = oh*32 + nt*16 + l15
  #pragma unroll
  for (int nt = 0; nt < 2; ++nt){
    float s1 = psum[nt], s2 = psq[nt];
    s1 += __shfl_xor(s1, 16, 64);  s2 += __shfl_xor(s2, 16, 64);
    s1 += __shfl_xor(s1, 32, 64);  s2 += __shfl_xor(s2, 32, 64);
    if (quad == 0){
      int o = oh*32 + nt*16 + l15;
      atomicAdd(&stats[bucket*128 + o], s1);
      atomicAdd(&stats[bucket*128 + 64 + o], s2);
    }
  }

  const size_t slab_off = (size_t)((int)blockIdx.y*2 + dpw) * OUTN_;
  const int h = h0 + hrow;
  #pragma unroll
  for (int mh = 0; mh < 2; ++mh)
    #pragma unroll
    for (int nt = 0; nt < 2; ++nt){
      int o = oh*32 + nt*16 + l15;
      #pragma unroll
      for (int rg = 0; rg < 4; ++rg){
        int w = mh*16 + quad*4 + rg;
        size_t idx = slab_off + ((size_t)(b*64 + o))*HW_ + h*W_ + w;
        maxp[idx] = __float2bfloat16(mmx[mh][nt][rg]);
        minp[idx] = __float2bfloat16(mmn[mh][nt][rg]);
      }
    }
}

// ---------------- final: reduce slabs, apply BN3+ReLU via monotonicity ----------------

__global__ void bevreduce_kernel(const bf16* __restrict__ minp, const bf16* __restrict__ maxp,
                                 const float* __restrict__ ss, float* __restrict__ out, int nslab){
  int j = blockIdx.x*blockDim.x + threadIdx.x;
  if (j >= OUTN_) return;
  int o = (j >> 12) & 63;
  float mx = -FLT_MAX, mn = FLT_MAX;
  for (int s = 0; s < nslab; ++s){
    mx = fmaxf(mx, __bfloat162float(maxp[(size_t)s*OUTN_ + j]));
    mn = fminf(mn, __bfloat162float(minp[(size_t)s*OUTN_ + j]));
  }
  float a = ss[o], sh = ss[64 + o];
  float v = (a >= 0.f) ? mx : mn;   // relu(a*z+s) monotone in z, direction sign(a)
  out[j] = fmaxf(fmaf(a, v, sh), 0.f);
}

// ---------------- BN finalize: sum buckets, scale/shift ----------------

__global__ void finalize_kernel(const float* __restrict__ stb, const float* __restrict__ gamma,
                                const float* __restrict__ beta, float* __restrict__ ss, int C){
  int c = threadIdx.x;
  if (c >= C) return;
  float s1 = 0.f, s2 = 0.f;
  for (int k = 0; k < NBUCK; ++k){
    s1 += stb[k*128 + c];
    s2 += stb[k*128 + C + c];
  }
  const float invCnt = 1.0f / (float)((size_t)B_*DHW_);
  float mean = s1 * invCnt;
  float var  = s2 * invCnt - mean*mean;
  float a = gamma[c] * rsqrtf(var + EPSV);
  ss[c]     = a;
  ss[C + c] = beta[c] - mean*a;
}

// ---------------- launch ----------------

extern "C" void kernel_launch(void* const* d_in, const int* in_sizes, int n_in,
                              void* d_out, int out_size, void* d_ws, size_t ws_size,
                              hipStream_t stream){
  const float* pc  = (const float*)d_in[0];
  const float* w1  = (const float*)d_in[1];
  const float* b1  = (const float*)d_in[2];
  const float* g1  = (const float*)d_in[3];
  const float* be1 = (const float*)d_in[4];
  const float* w2  = (const float*)d_in[5];
  const float* b2  = (const float*)d_in[6];
  const float* g2  = (const float*)d_in[7];
  const float* be2 = (const float*)d_in[8];
  const float* w3  = (const float*)d_in[9];
  const float* b3  = (const float*)d_in[10];
  const float* g3  = (const float*)d_in[11];
  const float* be3 = (const float*)d_in[12];
  const int N = in_sizes[0] / 6;  // (B=2, 3, N)
  float* out = (float*)d_out;

  char* wsb = (char*)d_ws;
  size_t off = 0;
  auto alloc = [&](size_t bytes)->char*{
    off = (off + 255) & ~(size_t)255;
    char* p = wsb + off; off += bytes; return p;
  };
  float* g0   = (float*)alloc((size_t)B_*DHW_*4);   // 4 MB
  float* wr1  = (float*)alloc(864*4);               // [27k][32o] fp32
  float* wr2  = (float*)alloc(55296*4);             // fp32 (fallback fused12)
  bf16*  wr2b = (bf16*) alloc(55296*2);             // conv2 LDS-image layout
  bf16*  wr3b = (bf16*) alloc(110592*2);            // conv3 [oh][ic][tap][iq][o'][j]
  float* mins = (float*)alloc(8*4);
  float* stb  = (float*)alloc((size_t)3*NBUCK*128*4); // bucketed stats, 192 KB
  float* ss   = (float*)alloc(3*128*4);

  constexpr int DCHUNK = 16;
  constexpr int NSLAB  = D_ / DCHUNK;               // 8 grid-slabs
  constexpr int NSLAB2 = NSLAB*2;                   // 16 partial slabs (dp-split)
  const size_t SX1  = (size_t)B_*DHW_*32*2;         // 64 MiB channel-last bf16
  const size_t SX2  = (size_t)B_*DHW_*64*2;         // 128 MiB channel-last bf16
  const size_t SMM  = (size_t)NSLAB2*OUTN_*2;       // 16.8 MiB per min/max array

  // regionR: x1 (64MiB) aliases minp/maxp (33.6MiB) — disjoint lifetimes
  const size_t prefixEnd = (off + 255) & ~(size_t)255;
  const bool useMfma2 = ws_size >= prefixEnd + SX1 + SX2 + 1024;

  char* regionR = alloc(useMfma2 ? SX1 : 2*SMM);
  bf16* maxp = (bf16*)regionR;
  bf16* minp = (bf16*)(regionR + SMM);
  bf16* x1   = (bf16*)regionR;
  bf16* x2   = (bf16*)alloc(SX2);

  float* st1 = stb;
  float* st2 = stb + (size_t)NBUCK*128;
  float* st3 = stb + (size_t)2*NBUCK*128;

  // prologue
  zero_kernel<<<(B_*DHW_ + 255)/256, 256, 0, stream>>>(g0, B_*DHW_);
  zero_kernel<<<(3*NBUCK*128 + 255)/256, 256, 0, stream>>>(stb, 3*NBUCK*128);
  min_kernel<<<B_*3, 256, 0, stream>>>(pc, mins, N);
  scatter_kernel<<<(B_*N + 255)/256, 256, 0, stream>>>(pc, mins, g0, N);
  reorder_kernel<<<(864 + 255)/256, 256, 0, stream>>>(w1, wr1, 1, 32);
  reorder_kernel<<<(55296 + 255)/256, 256, 0, stream>>>(w2, wr2, 32, 64);
  reorder2b_kernel<<<(55296 + 255)/256, 256, 0, stream>>>(w2, wr2b);
  reorder3b_kernel<<<(110592 + 255)/256, 256, 0, stream>>>(w3, wr3b);

  dim3 cgrid(16, 128, 2);                           // (8h-tiles, d, b)
  dim3 m2grid(32, NSLAB, 2);                        // conv2: 512 blocks x 512 thr
  dim3 m3grid(64, NSLAB, 2);                        // conv3: 1024 blocks x 512 thr

  if (useMfma2){
    conv1act_kernel<<<cgrid, 256, 0, stream>>>(g0, wr1, b1, x1, st1);
    finalize_kernel<<<1, 64, 0, stream>>>(st1, g1, be1, ss, 32);
    bnact_kernel<32><<<(int)(((size_t)B_*DHW_*4 + 255)/256), 256, 0, stream>>>(x1, ss);
    conv2mfma_kernel<DCHUNK><<<m2grid, 512, 0, stream>>>(x1, wr2b, b2, x2, st2);
  } else {
    convstats_kernel<<<cgrid, 256, 0, stream>>>(g0, wr1, b1, st1);
    finalize_kernel<<<1, 64, 0, stream>>>(st1, g1, be1, ss, 32);
    fused12_kernel<<<cgrid, 256, 0, stream>>>(g0, wr1, b1, ss, wr2, b2, x2, st2);
  }
  finalize_kernel<<<1, 64, 0, stream>>>(st2, g2, be2, ss + 128, 64);

  bnact_kernel<64><<<(int)(((size_t)B_*DHW_*8 + 255)/256), 256, 0, stream>>>(x2, ss + 128);

  conv3mfma_kernel<DCHUNK><<<m3grid, 512, 0, stream>>>(x2, wr3b, b3, st3, minp, maxp);
  finalize_kernel<<<1, 64, 0, stream>>>(st3, g3, be3, ss + 256, 64);
  bevreduce_kernel<<<(OUTN_ + 255)/256, 256, 0, stream>>>(minp, maxp, ss + 256, out, NSLAB2);
}